// Round 2
// baseline (985.369 us; speedup 1.0000x reference)
//
#include <hip/hip_runtime.h>
#include <hip/hip_bf16.h>
#include <cstdint>
#include <cstddef>

#define NND 50000
#define DIN 1488
#define DINP 1504
#define DHID 1024
#define DOUT 512
#define DHC 256
#define NE 800000
#define NHD 8

typedef __attribute__((ext_vector_type(8))) short short8;
typedef __attribute__((ext_vector_type(4))) short short4v;
typedef __attribute__((ext_vector_type(4))) float f32x4;
typedef unsigned short ushort_t;

__device__ __forceinline__ unsigned short f2bf(float f){
  union { float f; unsigned u; } v; v.f = f;
  unsigned r = v.u + 0x7fffu + ((v.u >> 16) & 1u);
  return (unsigned short)(r >> 16);
}
__device__ __forceinline__ float bf2f(unsigned short u){
  union { unsigned u; float f; } v; v.u = ((unsigned)u) << 16;
  return v.f;
}

__device__ __forceinline__ void async16(const void* g, void* l){
  __builtin_amdgcn_global_load_lds((__attribute__((address_space(1))) void*)g,
                                   (__attribute__((address_space(3))) void*)l, 16, 0, 0);
}

// ---------------- LayerNorm (fp32 -> bf16, pad 1488 -> 1504) ----------------
__global__ __launch_bounds__(256) void ln_kernel(const float* __restrict__ x,
                                                 const float* __restrict__ gw,
                                                 const float* __restrict__ bw,
                                                 ushort_t* __restrict__ xn){
  const int row = blockIdx.x;
  const float* xr = x + (size_t)row * DIN;
  const int t = threadIdx.x;
  float s = 0.f, sq = 0.f;
  for (int i = t*4; i < DIN; i += 1024){
    f32x4 v = *(const f32x4*)(xr + i);
    s  += v.x + v.y + v.z + v.w;
    sq += v.x*v.x + v.y*v.y + v.z*v.z + v.w*v.w;
  }
  for (int o = 32; o; o >>= 1){ s += __shfl_xor(s, o); sq += __shfl_xor(sq, o); }
  __shared__ float rs[4], rq[4];
  const int wid = t >> 6, lane = t & 63;
  if (!lane){ rs[wid] = s; rq[wid] = sq; }
  __syncthreads();
  s = rs[0]+rs[1]+rs[2]+rs[3]; sq = rq[0]+rq[1]+rq[2]+rq[3];
  const float mu = s * (1.f/DIN);
  const float var = sq * (1.f/DIN) - mu*mu;
  const float rstd = rsqrtf(var + 1e-5f);
  ushort_t* xo = xn + (size_t)row * DINP;
  for (int i = t*4; i < DIN; i += 1024){
    f32x4 v = *(const f32x4*)(xr + i);
    f32x4 gg = *(const f32x4*)(gw + i);
    f32x4 bb = *(const f32x4*)(bw + i);
    union { ushort_t u[4]; unsigned long long q; } o;
    o.u[0] = f2bf((v.x-mu)*rstd*gg.x + bb.x);
    o.u[1] = f2bf((v.y-mu)*rstd*gg.y + bb.y);
    o.u[2] = f2bf((v.z-mu)*rstd*gg.z + bb.z);
    o.u[3] = f2bf((v.w-mu)*rstd*gg.w + bb.w);
    *(unsigned long long*)(xo + i) = o.q;
  }
  if (t < (DINP - DIN)) xo[DIN + t] = 0;   // zero K-pad
}

// ---------------- transpose + cast fp32 [K,N] -> bf16 [N,Kp] ----------------
__global__ __launch_bounds__(256) void transpose_cast(const float* __restrict__ W,
                                                      ushort_t* __restrict__ WT,
                                                      int K, int Nn, int Kp){
  __shared__ float tile[32][33];
  const int tx = threadIdx.x & 31, ty = threadIdx.x >> 5;
  const int k0 = blockIdx.x*32, n0 = blockIdx.y*32;
  for (int i = ty; i < 32; i += 8){
    int k = k0 + i, n = n0 + tx;
    tile[i][tx] = (k < K && n < Nn) ? W[(size_t)k*Nn + n] : 0.f;
  }
  __syncthreads();
  for (int i = ty; i < 32; i += 8){
    int n = n0 + i, k = k0 + tx;
    if (n < Nn && k < Kp) WT[(size_t)n*Kp + k] = f2bf(tile[tx][i]);
  }
}

// ---------------- bf16 MFMA GEMM: C[M,Nn] = A[M,K] * BT[Nn,K]^T + bias ------
// K multiple of 32; Nn multiple of 128; M arbitrary (row-clamped loads).
template<int ACT, int BF16OUT>
__global__ __launch_bounds__(256) void gemm_bt(const ushort_t* __restrict__ A,
                                               const ushort_t* __restrict__ BT,
                                               const float* __restrict__ bias,
                                               void* __restrict__ Cout,
                                               int M, int Nn, int K){
  __shared__ __align__(16) ushort_t lA[128*32];
  __shared__ __align__(16) ushort_t lB[128*32];
  const int t = threadIdx.x, wid = t >> 6, lane = t & 63;
  const int brow = blockIdx.x*128, bcol = blockIdx.y*128;

  const int r0 = wid*32 + (lane >> 2);
  int ar0 = brow + r0, ar1 = brow + r0 + 16;
  ar0 = ar0 < M ? ar0 : M-1;  ar1 = ar1 < M ? ar1 : M-1;
  int bb0 = bcol + r0, bb1 = bcol + r0 + 16;
  bb0 = bb0 < Nn ? bb0 : Nn-1; bb1 = bb1 < Nn ? bb1 : Nn-1;
  const int kc = (lane & 3)*8;
  const ushort_t* pa0 = A  + (size_t)ar0*K + kc;
  const ushort_t* pa1 = A  + (size_t)ar1*K + kc;
  const ushort_t* pb0 = BT + (size_t)bb0*K + kc;
  const ushort_t* pb1 = BT + (size_t)bb1*K + kc;
  ushort_t* la0 = &lA[(wid*32)*32];
  ushort_t* la1 = &lA[(wid*32+16)*32];
  ushort_t* lb0 = &lB[(wid*32)*32];
  ushort_t* lb1 = &lB[(wid*32+16)*32];

  f32x4 acc[4][4];
  #pragma unroll
  for (int i=0;i<4;i++)
    #pragma unroll
    for (int j=0;j<4;j++) acc[i][j] = (f32x4){0.f,0.f,0.f,0.f};

  const int wr = (wid >> 1)*64, wc = (wid & 1)*64;
  const int fo = (lane & 15)*32 + (lane >> 4)*8;   // fragment ds_read offset

  const int nk = K >> 5;
  for (int kt = 0; kt < nk; ++kt){
    async16(pa0, la0); async16(pa1, la1);
    async16(pb0, lb0); async16(pb1, lb1);
    pa0 += 32; pa1 += 32; pb0 += 32; pb1 += 32;
    __syncthreads();                 // drains vmcnt -> LDS tile visible
    short8 af[4], bfr[4];
    #pragma unroll
    for (int m=0;m<4;m++) af[m]  = *(const short8*)&lA[(wr + m*16)*32 + fo];
    #pragma unroll
    for (int n=0;n<4;n++) bfr[n] = *(const short8*)&lB[(wc + n*16)*32 + fo];
    #pragma unroll
    for (int m=0;m<4;m++)
      #pragma unroll
      for (int n=0;n<4;n++)
        acc[m][n] = __builtin_amdgcn_mfma_f32_16x16x32_bf16(af[m], bfr[n], acc[m][n], 0, 0, 0);
    __syncthreads();
  }

  #pragma unroll
  for (int n=0;n<4;n++){
    const int col = bcol + wc + n*16 + (lane & 15);
    const float bv = bias ? bias[col] : 0.f;
    #pragma unroll
    for (int m=0;m<4;m++){
      const int row0 = brow + wr + m*16 + (lane >> 4)*4;
      #pragma unroll
      for (int j=0;j<4;j++){
        const int row = row0 + j;
        if (row < M){
          float v = acc[m][n][j] + bv;
          if (ACT == 1) v = v > 0.f ? v : 0.f;
          if (BF16OUT) ((ushort_t*)Cout)[(size_t)row*Nn + col] = f2bf(v);
          else         ((float*)Cout)[(size_t)row*Nn + col] = v;
        }
      }
    }
  }
}

// ---------------- attention scores a_src/a_dst: [N,8] = sum_c g*att --------
__global__ __launch_bounds__(256) void att_scores(const ushort_t* __restrict__ gm,
                                                  const float* __restrict__ att_s,
                                                  const float* __restrict__ att_d,
                                                  float* __restrict__ asrc,
                                                  float* __restrict__ adst){
  __shared__ float ss[256], sd[256];
  const int t = threadIdx.x;
  ss[t] = att_s[t]; sd[t] = att_d[t];
  __syncthreads();
  const int idx = blockIdx.x*256 + t;
  if (idx >= NND*NHD) return;
  const int n = idx >> 3, h = idx & 7;
  const ushort_t* gr = gm + (size_t)n*DHC + h*32;
  float a = 0.f, d = 0.f;
  #pragma unroll
  for (int c0 = 0; c0 < 32; c0 += 8){
    short8 gv = *(const short8*)(gr + c0);
    #pragma unroll
    for (int j = 0; j < 8; ++j){
      float g = bf2f((ushort_t)gv[j]);
      a += g*ss[h*32+c0+j]; d += g*sd[h*32+c0+j];
    }
  }
  asrc[idx] = a; adst[idx] = d;
}

// ---------------- CSR build ----------------
__global__ void init_cnt(int* cnt){
  int i = blockIdx.x*256 + threadIdx.x;
  if (i < NND) cnt[i] = 1;                       // self-loop
}
__global__ void count_edges(const int* __restrict__ ei, int* cnt){
  int e = blockIdx.x*256 + threadIdx.x;
  if (e < NE) atomicAdd(&cnt[ei[NE + e]], 1);
}
__global__ __launch_bounds__(1024) void scan_kernel(const int* __restrict__ cnt,
                                                    int* __restrict__ offs,
                                                    int* __restrict__ cur){
  __shared__ int buf[1024];
  const int t = threadIdx.x;
  const int chunk = (NND + 1023) >> 10;
  const int s0 = t*chunk, s1 = (s0 + chunk < NND) ? s0 + chunk : NND;
  int s = 0;
  for (int i = s0; i < s1; ++i) s += cnt[i];
  buf[t] = s; __syncthreads();
  for (int o = 1; o < 1024; o <<= 1){
    int x = (t >= o) ? buf[t-o] : 0;
    __syncthreads();
    buf[t] += x;
    __syncthreads();
  }
  int run = buf[t] - s;                          // exclusive prefix
  for (int i = s0; i < s1; ++i){
    int c = cnt[i];
    cur[i] = run;
    run += c;
    offs[i+1] = run;
  }
  if (t == 0) offs[0] = 0;
}
__global__ void fill_self(int* cur, int* eidx){
  int i = blockIdx.x*256 + threadIdx.x;
  if (i < NND){ int p = atomicAdd(&cur[i], 1); eidx[p] = i; }
}
__global__ void fill_edges(const int* __restrict__ ei, int* cur, int* eidx){
  int e = blockIdx.x*256 + threadIdx.x;
  if (e < NE){
    int src = ei[e], dst = ei[NE + e];
    int p = atomicAdd(&cur[dst], 1);
    eidx[p] = src;
  }
}

// ---------------- fused GAT aggregate + elu + residual (1 wave / node) -----
__global__ __launch_bounds__(256) void gat_agg(const int* __restrict__ offs,
                                               const int* __restrict__ eidx,
                                               const float* __restrict__ asrc,
                                               const float* __restrict__ adst,
                                               const ushort_t* __restrict__ gm,
                                               const float* __restrict__ res,
                                               const float* __restrict__ bg,
                                               float* __restrict__ out){
  const int wid = threadIdx.x >> 6, lane = threadIdx.x & 63;
  const int node = blockIdx.x*4 + wid;
  if (node >= NND) return;
  const int h = lane >> 3;
  const int e0 = offs[node], deg = offs[node+1] - e0;
  const float adv = adst[node*NHD + h];

  float mx = -1e30f;
  for (int j = (lane & 7); j < deg; j += 8){
    int s = eidx[e0 + j];
    float e = asrc[s*NHD + h] + adv; e = e > 0.f ? e : 0.2f*e;
    mx = fmaxf(mx, e);
  }
  mx = fmaxf(mx, __shfl_xor(mx, 1));
  mx = fmaxf(mx, __shfl_xor(mx, 2));
  mx = fmaxf(mx, __shfl_xor(mx, 4));

  float sm = 0.f;
  for (int j = (lane & 7); j < deg; j += 8){
    int s = eidx[e0 + j];
    float e = asrc[s*NHD + h] + adv; e = e > 0.f ? e : 0.2f*e;
    sm += __expf(e - mx);
  }
  sm += __shfl_xor(sm, 1); sm += __shfl_xor(sm, 2); sm += __shfl_xor(sm, 4);
  const float inv = 1.f/(sm + 1e-16f);

  const int c4 = lane*4;                          // channels [c4, c4+4) ; head c4/32 == h
  f32x4 acc = {0.f,0.f,0.f,0.f};
  for (int j = 0; j < deg; ++j){
    int s = eidx[e0 + j];
    float e = asrc[s*NHD + h] + adv; e = e > 0.f ? e : 0.2f*e;
    float w = __expf(e - mx)*inv;
    short4v gv = *(const short4v*)(gm + (size_t)s*DHC + c4);
    acc.x += w*bf2f((ushort_t)gv.x);
    acc.y += w*bf2f((ushort_t)gv.y);
    acc.z += w*bf2f((ushort_t)gv.z);
    acc.w += w*bf2f((ushort_t)gv.w);
  }
  f32x4 bgv = *(const f32x4*)(bg + c4);
  f32x4 rv  = *(const f32x4*)(res + (size_t)node*DHC + c4);
  f32x4 o;
  #pragma unroll
  for (int q = 0; q < 4; ++q){
    float v = acc[q] + bgv[q];
    v = v > 0.f ? v : expm1f(v);
    o[q] = v + rv[q];
  }
  *(f32x4*)(out + (size_t)node*DHC + c4) = o;
}

extern "C" void kernel_launch(void* const* d_in, const int* in_sizes, int n_in,
                              void* d_out, int out_size, void* d_ws, size_t ws_size,
                              hipStream_t stream){
  (void)in_sizes; (void)n_in; (void)out_size; (void)ws_size;
  const float* x     = (const float*)d_in[0];
  const int*   ei    = (const int*)d_in[1];          // int32 per harness convention
  const float* ln_g  = (const float*)d_in[2];
  const float* ln_b  = (const float*)d_in[3];
  const float* W1    = (const float*)d_in[4];
  const float* b1    = (const float*)d_in[5];
  const float* W2    = (const float*)d_in[6];
  const float* b2    = (const float*)d_in[7];
  const float* Wr    = (const float*)d_in[8];
  const float* br    = (const float*)d_in[9];
  const float* Wg    = (const float*)d_in[10];
  const float* att_s = (const float*)d_in[11];
  const float* att_d = (const float*)d_in[12];
  const float* bg    = (const float*)d_in[13];
  float* out = (float*)d_out;

  char* p = (char*)d_ws;
  // persistent region
  ushort_t* xn  = (ushort_t*)(p);                    // [0, 150,400,000)
  ushort_t* h1  = (ushort_t*)(p + 150400000);        // 102,400,000
  ushort_t* W1T = (ushort_t*)(p + 252800000);        //   3,080,192
  ushort_t* W2T = (ushort_t*)(p + 255880192);        //   1,048,576
  ushort_t* WrT = (ushort_t*)(p + 256928768);        //     262,144
  ushort_t* WgT = (ushort_t*)(p + 257190912);        //     262,144 -> end 257,453,056
  // aliased into xn region (xn dead after gemm1)
  ushort_t* hb   = (ushort_t*)(p + 0);               //  51,200,000 (bf16)
  float*    res  = (float*)(p + 51200000);           //  51,200,000 (f32)
  ushort_t* gm   = (ushort_t*)(p + 102400000);       //  25,600,000 (bf16)
  float*    asrc = (float*)(p + 128000000);          //   1,600,000
  float*    adst = (float*)(p + 129600000);          //   1,600,000
  int*      cnt  = (int*)(p + 131200000);            //     200,000
  int*      offs = (int*)(p + 131400064);            //     200,004
  int*      cur  = (int*)(p + 131600128);            //     200,000
  int*      eidx = (int*)(p + 131800192);            //   3,400,000 -> end 135,200,192

  // weight prep (bf16, transposed, K-padded)
  transpose_cast<<<dim3(47,32), 256, 0, stream>>>(W1, W1T, DIN,  DHID, DINP);
  transpose_cast<<<dim3(32,16), 256, 0, stream>>>(W2, W2T, DHID, DOUT, DHID);
  transpose_cast<<<dim3(16, 8), 256, 0, stream>>>(Wr, WrT, DOUT, DHC,  DOUT);
  transpose_cast<<<dim3(16, 8), 256, 0, stream>>>(Wg, WgT, DOUT, DHC,  DOUT);

  ln_kernel<<<NND, 256, 0, stream>>>(x, ln_g, ln_b, xn);

  gemm_bt<1,1><<<dim3(391, 8), 256, 0, stream>>>(xn, W1T, b1, h1,  NND, DHID, DINP);
  gemm_bt<0,1><<<dim3(391, 4), 256, 0, stream>>>(h1, W2T, b2, hb,  NND, DOUT, DHID);
  gemm_bt<0,0><<<dim3(391, 2), 256, 0, stream>>>(hb, WrT, br, res, NND, DHC,  DOUT);
  gemm_bt<0,1><<<dim3(391, 2), 256, 0, stream>>>(hb, WgT, (const float*)nullptr, gm, NND, DHC, DOUT);

  att_scores<<<(NND*NHD + 255)/256, 256, 0, stream>>>(gm, att_s, att_d, asrc, adst);

  init_cnt<<<(NND + 255)/256, 256, 0, stream>>>(cnt);
  count_edges<<<(NE + 255)/256, 256, 0, stream>>>(ei, cnt);
  scan_kernel<<<1, 1024, 0, stream>>>(cnt, offs, cur);
  fill_self<<<(NND + 255)/256, 256, 0, stream>>>(cur, eidx);
  fill_edges<<<(NE + 255)/256, 256, 0, stream>>>(ei, cur, eidx);

  gat_agg<<<(NND + 3)/4, 256, 0, stream>>>(offs, eidx, asrc, adst, gm, res, bg, out);
}

// Round 3
// 924.336 us; speedup vs baseline: 1.0660x; 1.0660x over previous
//
#include <hip/hip_runtime.h>
#include <hip/hip_bf16.h>
#include <cstdint>
#include <cstddef>

#define NND 50000
#define DIN 1488
#define DINP 1504
#define DHID 1024
#define DOUT 512
#define DHC 256
#define NE 800000
#define NHD 8
#define SPLITC 256

typedef __attribute__((ext_vector_type(8))) short short8;
typedef __attribute__((ext_vector_type(4))) short short4v;
typedef __attribute__((ext_vector_type(4))) float f32x4;
typedef unsigned short ushort_t;

__device__ __forceinline__ unsigned short f2bf(float f){
  union { float f; unsigned u; } v; v.f = f;
  unsigned r = v.u + 0x7fffu + ((v.u >> 16) & 1u);
  return (unsigned short)(r >> 16);
}
__device__ __forceinline__ float bf2f(unsigned short u){
  union { unsigned u; float f; } v; v.u = ((unsigned)u) << 16;
  return v.f;
}

__device__ __forceinline__ void async16(const void* g, void* l){
  __builtin_amdgcn_global_load_lds((__attribute__((address_space(1))) void*)g,
                                   (__attribute__((address_space(3))) void*)l, 16, 0, 0);
}

// ---------------- LayerNorm (fp32 -> bf16, pad 1488 -> 1504) ----------------
__global__ __launch_bounds__(256) void ln_kernel(const float* __restrict__ x,
                                                 const float* __restrict__ gw,
                                                 const float* __restrict__ bw,
                                                 ushort_t* __restrict__ xn){
  const int row = blockIdx.x;
  const float* xr = x + (size_t)row * DIN;
  const int t = threadIdx.x;
  float s = 0.f, sq = 0.f;
  for (int i = t*4; i < DIN; i += 1024){
    f32x4 v = *(const f32x4*)(xr + i);
    s  += v.x + v.y + v.z + v.w;
    sq += v.x*v.x + v.y*v.y + v.z*v.z + v.w*v.w;
  }
  for (int o = 32; o; o >>= 1){ s += __shfl_xor(s, o); sq += __shfl_xor(sq, o); }
  __shared__ float rs[4], rq[4];
  const int wid = t >> 6, lane = t & 63;
  if (!lane){ rs[wid] = s; rq[wid] = sq; }
  __syncthreads();
  s = rs[0]+rs[1]+rs[2]+rs[3]; sq = rq[0]+rq[1]+rq[2]+rq[3];
  const float mu = s * (1.f/DIN);
  const float var = sq * (1.f/DIN) - mu*mu;
  const float rstd = rsqrtf(var + 1e-5f);
  ushort_t* xo = xn + (size_t)row * DINP;
  for (int i = t*4; i < DIN; i += 1024){
    f32x4 v = *(const f32x4*)(xr + i);
    f32x4 gg = *(const f32x4*)(gw + i);
    f32x4 bb = *(const f32x4*)(bw + i);
    union { ushort_t u[4]; unsigned long long q; } o;
    o.u[0] = f2bf((v.x-mu)*rstd*gg.x + bb.x);
    o.u[1] = f2bf((v.y-mu)*rstd*gg.y + bb.y);
    o.u[2] = f2bf((v.z-mu)*rstd*gg.z + bb.z);
    o.u[3] = f2bf((v.w-mu)*rstd*gg.w + bb.w);
    *(unsigned long long*)(xo + i) = o.q;
  }
  if (t < (DINP - DIN)) xo[DIN + t] = 0;   // zero K-pad
}

// ---------------- transpose + cast fp32 [K,N] -> bf16 [N,Kp] ----------------
__global__ __launch_bounds__(256) void transpose_cast(const float* __restrict__ W,
                                                      ushort_t* __restrict__ WT,
                                                      int K, int Nn, int Kp){
  __shared__ float tile[32][33];
  const int tx = threadIdx.x & 31, ty = threadIdx.x >> 5;
  const int k0 = blockIdx.x*32, n0 = blockIdx.y*32;
  for (int i = ty; i < 32; i += 8){
    int k = k0 + i, n = n0 + tx;
    tile[i][tx] = (k < K && n < Nn) ? W[(size_t)k*Nn + n] : 0.f;
  }
  __syncthreads();
  for (int i = ty; i < 32; i += 8){
    int n = n0 + i, k = k0 + tx;
    if (n < Nn && k < Kp) WT[(size_t)n*Kp + k] = f2bf(tile[tx][i]);
  }
}

// ---------------- bf16 MFMA GEMM: C[M,Nn] = A[M,K] * BT[Nn,K]^T + bias ------
// MODE 0: f32 out. MODE 1: bf16 out. MODE 2: split (bcol<SPLITC -> f32 out0
// with bias; else bf16 out1, no bias, col-SPLITC). 1D grid, col-fastest.
template<int ACT, int MODE>
__global__ __launch_bounds__(256) void gemm_bt(const ushort_t* __restrict__ A,
                                               const ushort_t* __restrict__ BT,
                                               const float* __restrict__ bias,
                                               void* __restrict__ out0,
                                               void* __restrict__ out1,
                                               int M, int Nn, int K, int CB){
  __shared__ __align__(16) char smem[16384];
  ushort_t* lA = (ushort_t*)smem;           // 128x32 bf16 = 8KB
  ushort_t* lB = (ushort_t*)(smem + 8192);  // 128x32 bf16 = 8KB
  const int t = threadIdx.x, wid = t >> 6, lane = t & 63;
  const int bid = blockIdx.x;
  const int brow = (bid / CB) * 128, bcol = (bid % CB) * 128;

  const int r0 = wid*32 + (lane >> 2);
  int ar0 = brow + r0, ar1 = brow + r0 + 16;
  ar0 = ar0 < M ? ar0 : M-1;  ar1 = ar1 < M ? ar1 : M-1;
  int bb0 = bcol + r0, bb1 = bcol + r0 + 16;
  bb0 = bb0 < Nn ? bb0 : Nn-1; bb1 = bb1 < Nn ? bb1 : Nn-1;
  const int kc = (lane & 3)*8;
  const ushort_t* pa0 = A  + (size_t)ar0*K + kc;
  const ushort_t* pa1 = A  + (size_t)ar1*K + kc;
  const ushort_t* pb0 = BT + (size_t)bb0*K + kc;
  const ushort_t* pb1 = BT + (size_t)bb1*K + kc;
  ushort_t* la0 = &lA[(wid*32)*32];
  ushort_t* la1 = &lA[(wid*32+16)*32];
  ushort_t* lb0 = &lB[(wid*32)*32];
  ushort_t* lb1 = &lB[(wid*32+16)*32];

  f32x4 acc[4][4];
  #pragma unroll
  for (int i=0;i<4;i++)
    #pragma unroll
    for (int j=0;j<4;j++) acc[i][j] = (f32x4){0.f,0.f,0.f,0.f};

  const int wr = (wid >> 1)*64, wc = (wid & 1)*64;
  const int fo = (lane & 15)*32 + (lane >> 4)*8;   // fragment ds_read offset

  const int nk = K >> 5;
  for (int kt = 0; kt < nk; ++kt){
    async16(pa0, la0); async16(pa1, la1);
    async16(pb0, lb0); async16(pb1, lb1);
    pa0 += 32; pa1 += 32; pb0 += 32; pb1 += 32;
    __syncthreads();                 // drains vmcnt -> LDS tile visible
    short8 af[4], bfr[4];
    #pragma unroll
    for (int m=0;m<4;m++) af[m]  = *(const short8*)&lA[(wr + m*16)*32 + fo];
    #pragma unroll
    for (int n=0;n<4;n++) bfr[n] = *(const short8*)&lB[(wc + n*16)*32 + fo];
    #pragma unroll
    for (int m=0;m<4;m++)
      #pragma unroll
      for (int n=0;n<4;n++)
        acc[m][n] = __builtin_amdgcn_mfma_f32_16x16x32_bf16(af[m], bfr[n], acc[m][n], 0, 0, 0);
    __syncthreads();
  }

  // ---- epilogue: repack through LDS, coalesced stores, 4 chunks of 32 rows
  bool isf32;
  float* outF = nullptr; ushort_t* outB = nullptr; int ostride = 0, ocb = 0;
  if (MODE == 0){ isf32 = true;  outF = (float*)out0;    ostride = Nn; ocb = bcol; }
  else if (MODE == 1){ isf32 = false; outB = (ushort_t*)out0; ostride = Nn; ocb = bcol; }
  else {
    if (bcol < SPLITC){ isf32 = true;  outF = (float*)out0;    ostride = SPLITC;      ocb = bcol; }
    else              { isf32 = false; outB = (ushort_t*)out1; ostride = Nn - SPLITC; ocb = bcol - SPLITC; }
  }
  float bv[4];
  #pragma unroll
  for (int n=0;n<4;n++){
    const int col = wc + n*16 + (lane & 15);
    float b = 0.f;
    if (MODE == 2){ if (isf32 && bias) b = bias[bcol + col]; }
    else if (bias) b = bias[bcol + col];
    bv[n] = b;
  }
  float* sF = (float*)smem;
  ushort_t* sB = (ushort_t*)smem;
  const int trow = t >> 3, tc16 = (t & 7) * 16;
  #pragma unroll
  for (int c = 0; c < 4; ++c){
    __syncthreads();
    if ((wid >> 1) == (c >> 1)){
      #pragma unroll
      for (int mm = 0; mm < 2; ++mm){
        const int m = 2*(c & 1) + mm;
        const int rbase = m*16 + (lane >> 4)*4 - (c & 1)*32;   // 0..28
        #pragma unroll
        for (int n = 0; n < 4; ++n){
          const int col = wc + n*16 + (lane & 15);
          #pragma unroll
          for (int j = 0; j < 4; ++j){
            float v = acc[m][n][j] + bv[n];
            if (ACT) v = v > 0.f ? v : 0.f;
            if (isf32) sF[(rbase + j)*128 + col] = v;
            else       sB[(rbase + j)*128 + col] = f2bf(v);
          }
        }
      }
    }
    __syncthreads();
    const int grow = brow + c*32 + trow;
    if (grow < M){
      if (isf32){
        float* dst = outF + (size_t)grow*ostride + ocb + tc16;
        const float* src = sF + trow*128 + tc16;
        #pragma unroll
        for (int q = 0; q < 4; ++q) ((f32x4*)dst)[q] = ((const f32x4*)src)[q];
      } else {
        ushort_t* dst = outB + (size_t)grow*ostride + ocb + tc16;
        const ushort_t* src = sB + trow*128 + tc16;
        #pragma unroll
        for (int q = 0; q < 2; ++q) ((short8*)dst)[q] = ((const short8*)src)[q];
      }
    }
  }
}

// ---------------- attention scores a_src/a_dst: [N,8] = sum_c g*att --------
__global__ __launch_bounds__(256) void att_scores(const ushort_t* __restrict__ gm,
                                                  const float* __restrict__ att_s,
                                                  const float* __restrict__ att_d,
                                                  float* __restrict__ asrc,
                                                  float* __restrict__ adst){
  __shared__ float ss[256], sd[256];
  const int t = threadIdx.x;
  ss[t] = att_s[t]; sd[t] = att_d[t];
  __syncthreads();
  const int idx = blockIdx.x*256 + t;
  if (idx >= NND*NHD) return;
  const int n = idx >> 3, h = idx & 7;
  const ushort_t* gr = gm + (size_t)n*DHC + h*32;
  float a = 0.f, d = 0.f;
  #pragma unroll
  for (int c0 = 0; c0 < 32; c0 += 8){
    short8 gv = *(const short8*)(gr + c0);
    #pragma unroll
    for (int j = 0; j < 8; ++j){
      float g = bf2f((ushort_t)gv[j]);
      a += g*ss[h*32+c0+j]; d += g*sd[h*32+c0+j];
    }
  }
  asrc[idx] = a; adst[idx] = d;
}

// ---------------- CSR build ----------------
__global__ void init_cnt(int* cnt){
  int i = blockIdx.x*256 + threadIdx.x;
  if (i < NND) cnt[i] = 1;                       // self-loop
}
__global__ void count_edges(const int* __restrict__ ei, int* cnt){
  int e = blockIdx.x*256 + threadIdx.x;
  if (e < NE) atomicAdd(&cnt[ei[NE + e]], 1);
}
__global__ __launch_bounds__(1024) void scan_kernel(const int* __restrict__ cnt,
                                                    int* __restrict__ offs,
                                                    int* __restrict__ cur){
  __shared__ int buf[1024];
  const int t = threadIdx.x;
  const int chunk = (NND + 1023) >> 10;
  const int s0 = t*chunk, s1 = (s0 + chunk < NND) ? s0 + chunk : NND;
  int s = 0;
  for (int i = s0; i < s1; ++i) s += cnt[i];
  buf[t] = s; __syncthreads();
  for (int o = 1; o < 1024; o <<= 1){
    int x = (t >= o) ? buf[t-o] : 0;
    __syncthreads();
    buf[t] += x;
    __syncthreads();
  }
  int run = buf[t] - s;                          // exclusive prefix
  for (int i = s0; i < s1; ++i){
    int c = cnt[i];
    cur[i] = run;
    run += c;
    offs[i+1] = run;
  }
  if (t == 0) offs[0] = 0;
}
__global__ void fill_self(int* cur, int* eidx){
  int i = blockIdx.x*256 + threadIdx.x;
  if (i < NND){ int p = atomicAdd(&cur[i], 1); eidx[p] = i; }
}
__global__ void fill_edges(const int* __restrict__ ei, int* cur, int* eidx){
  int e = blockIdx.x*256 + threadIdx.x;
  if (e < NE){
    int src = ei[e], dst = ei[NE + e];
    int p = atomicAdd(&cur[dst], 1);
    eidx[p] = src;
  }
}

// ---------------- fused GAT aggregate + elu + residual (1 wave / node) -----
__global__ __launch_bounds__(256) void gat_agg(const int* __restrict__ offs,
                                               const int* __restrict__ eidx,
                                               const float* __restrict__ asrc,
                                               const float* __restrict__ adst,
                                               const ushort_t* __restrict__ gm,
                                               const float* __restrict__ res,
                                               const float* __restrict__ bg,
                                               float* __restrict__ out){
  const int wid = threadIdx.x >> 6, lane = threadIdx.x & 63;
  const int node = blockIdx.x*4 + wid;
  if (node >= NND) return;
  const int h = lane >> 3;
  const int e0 = offs[node], deg = offs[node+1] - e0;
  const float adv = adst[node*NHD + h];

  float mx = -1e30f;
  for (int j = (lane & 7); j < deg; j += 8){
    int s = eidx[e0 + j];
    float e = asrc[s*NHD + h] + adv; e = e > 0.f ? e : 0.2f*e;
    mx = fmaxf(mx, e);
  }
  mx = fmaxf(mx, __shfl_xor(mx, 1));
  mx = fmaxf(mx, __shfl_xor(mx, 2));
  mx = fmaxf(mx, __shfl_xor(mx, 4));

  float sm = 0.f;
  for (int j = (lane & 7); j < deg; j += 8){
    int s = eidx[e0 + j];
    float e = asrc[s*NHD + h] + adv; e = e > 0.f ? e : 0.2f*e;
    sm += __expf(e - mx);
  }
  sm += __shfl_xor(sm, 1); sm += __shfl_xor(sm, 2); sm += __shfl_xor(sm, 4);
  const float inv = 1.f/(sm + 1e-16f);

  const int c4 = lane*4;                          // channels [c4, c4+4) ; head c4/32 == h
  f32x4 acc = {0.f,0.f,0.f,0.f};
  for (int j = 0; j < deg; ++j){
    int s = eidx[e0 + j];
    float e = asrc[s*NHD + h] + adv; e = e > 0.f ? e : 0.2f*e;
    float w = __expf(e - mx)*inv;
    short4v gv = *(const short4v*)(gm + (size_t)s*DHC + c4);
    acc.x += w*bf2f((ushort_t)gv.x);
    acc.y += w*bf2f((ushort_t)gv.y);
    acc.z += w*bf2f((ushort_t)gv.z);
    acc.w += w*bf2f((ushort_t)gv.w);
  }
  f32x4 bgv = *(const f32x4*)(bg + c4);
  f32x4 rv  = *(const f32x4*)(res + (size_t)node*DHC + c4);
  f32x4 o;
  #pragma unroll
  for (int q = 0; q < 4; ++q){
    float v = acc[q] + bgv[q];
    v = v > 0.f ? v : expm1f(v);
    o[q] = v + rv[q];
  }
  *(f32x4*)(out + (size_t)node*DHC + c4) = o;
}

extern "C" void kernel_launch(void* const* d_in, const int* in_sizes, int n_in,
                              void* d_out, int out_size, void* d_ws, size_t ws_size,
                              hipStream_t stream){
  (void)in_sizes; (void)n_in; (void)out_size; (void)ws_size;
  const float* x     = (const float*)d_in[0];
  const int*   ei    = (const int*)d_in[1];          // int32 per harness convention
  const float* ln_g  = (const float*)d_in[2];
  const float* ln_b  = (const float*)d_in[3];
  const float* W1    = (const float*)d_in[4];
  const float* b1    = (const float*)d_in[5];
  const float* W2    = (const float*)d_in[6];
  const float* b2    = (const float*)d_in[7];
  const float* Wr    = (const float*)d_in[8];
  const float* br    = (const float*)d_in[9];
  const float* Wg    = (const float*)d_in[10];
  const float* att_s = (const float*)d_in[11];
  const float* att_d = (const float*)d_in[12];
  const float* bg    = (const float*)d_in[13];
  float* out = (float*)d_out;

  char* p = (char*)d_ws;
  // persistent region
  ushort_t* xn   = (ushort_t*)(p);                   // [0, 150,400,000)
  ushort_t* h1   = (ushort_t*)(p + 150400000);       // 102,400,000
  ushort_t* W1T  = (ushort_t*)(p + 252800000);       //   3,080,192
  ushort_t* W2T  = (ushort_t*)(p + 255880192);       //   1,048,576
  ushort_t* WrgT = (ushort_t*)(p + 256928768);       //     524,288 -> end 257,453,056
  // aliased into xn region (xn dead after gemm1)
  ushort_t* hb   = (ushort_t*)(p + 0);               //  51,200,000 (bf16)
  float*    res  = (float*)(p + 51200000);           //  51,200,000 (f32)
  ushort_t* gm   = (ushort_t*)(p + 102400000);       //  25,600,000 (bf16)
  float*    asrc = (float*)(p + 128000000);          //   1,600,000
  float*    adst = (float*)(p + 129600000);          //   1,600,000
  int*      cnt  = (int*)(p + 131200000);            //     200,000
  int*      offs = (int*)(p + 131400064);            //     200,004
  int*      cur  = (int*)(p + 131600128);            //     200,000
  int*      eidx = (int*)(p + 131800192);            //   3,400,000 -> end 135,200,192

  // weight prep (bf16, transposed, K-padded)
  transpose_cast<<<dim3(47,32), 256, 0, stream>>>(W1, W1T, DIN,  DHID, DINP);
  transpose_cast<<<dim3(32,16), 256, 0, stream>>>(W2, W2T, DHID, DOUT, DHID);
  transpose_cast<<<dim3(16, 8), 256, 0, stream>>>(Wr, WrgT,            DOUT, DHC, DOUT);
  transpose_cast<<<dim3(16, 8), 256, 0, stream>>>(Wg, WrgT + 256*DOUT, DOUT, DHC, DOUT);

  ln_kernel<<<NND, 256, 0, stream>>>(x, ln_g, ln_b, xn);

  gemm_bt<1,1><<<391*8, 256, 0, stream>>>(xn, W1T, b1, h1, nullptr, NND, DHID, DINP, 8);
  gemm_bt<0,1><<<391*4, 256, 0, stream>>>(h1, W2T, b2, hb, nullptr, NND, DOUT, DHID, 4);
  gemm_bt<0,2><<<391*4, 256, 0, stream>>>(hb, WrgT, br, res, gm, NND, 2*DHC, DOUT, 4);

  att_scores<<<(NND*NHD + 255)/256, 256, 0, stream>>>(gm, att_s, att_d, asrc, adst);

  init_cnt<<<(NND + 255)/256, 256, 0, stream>>>(cnt);
  count_edges<<<(NE + 255)/256, 256, 0, stream>>>(ei, cnt);
  scan_kernel<<<1, 1024, 0, stream>>>(cnt, offs, cur);
  fill_self<<<(NND + 255)/256, 256, 0, stream>>>(cur, eidx);
  fill_edges<<<(NE + 255)/256, 256, 0, stream>>>(ei, cur, eidx);

  gat_agg<<<(NND + 3)/4, 256, 0, stream>>>(offs, eidx, asrc, adst, gm, res, bg, out);
}

// Round 4
// 921.504 us; speedup vs baseline: 1.0693x; 1.0031x over previous
//
#include <hip/hip_runtime.h>
#include <hip/hip_bf16.h>
#include <cstdint>
#include <cstddef>

#define NND 50000
#define DIN 1488
#define DINP 1504
#define DHID 1024
#define DOUT 512
#define DHC 256
#define NE 800000
#define NHD 8
#define SPLITC 256

typedef __attribute__((ext_vector_type(8))) short short8;
typedef __attribute__((ext_vector_type(4))) short short4v;
typedef __attribute__((ext_vector_type(4))) float f32x4;
typedef unsigned short ushort_t;

__device__ __forceinline__ unsigned short f2bf(float f){
  union { float f; unsigned u; } v; v.f = f;
  unsigned r = v.u + 0x7fffu + ((v.u >> 16) & 1u);
  return (unsigned short)(r >> 16);
}
__device__ __forceinline__ float bf2f(unsigned short u){
  union { unsigned u; float f; } v; v.u = ((unsigned)u) << 16;
  return v.f;
}

__device__ __forceinline__ void async16(const void* g, void* l){
  __builtin_amdgcn_global_load_lds((__attribute__((address_space(1))) void*)g,
                                   (__attribute__((address_space(3))) void*)l, 16, 0, 0);
}

// ---------------- LayerNorm (fp32 -> bf16, pad 1488 -> 1504) ----------------
__global__ __launch_bounds__(256) void ln_kernel(const float* __restrict__ x,
                                                 const float* __restrict__ gw,
                                                 const float* __restrict__ bw,
                                                 ushort_t* __restrict__ xn){
  const int row = blockIdx.x;
  const float* xr = x + (size_t)row * DIN;
  const int t = threadIdx.x;
  float s = 0.f, sq = 0.f;
  for (int i = t*4; i < DIN; i += 1024){
    f32x4 v = *(const f32x4*)(xr + i);
    s  += v.x + v.y + v.z + v.w;
    sq += v.x*v.x + v.y*v.y + v.z*v.z + v.w*v.w;
  }
  for (int o = 32; o; o >>= 1){ s += __shfl_xor(s, o); sq += __shfl_xor(sq, o); }
  __shared__ float rs[4], rq[4];
  const int wid = t >> 6, lane = t & 63;
  if (!lane){ rs[wid] = s; rq[wid] = sq; }
  __syncthreads();
  s = rs[0]+rs[1]+rs[2]+rs[3]; sq = rq[0]+rq[1]+rq[2]+rq[3];
  const float mu = s * (1.f/DIN);
  const float var = sq * (1.f/DIN) - mu*mu;
  const float rstd = rsqrtf(var + 1e-5f);
  ushort_t* xo = xn + (size_t)row * DINP;
  for (int i = t*4; i < DIN; i += 1024){
    f32x4 v = *(const f32x4*)(xr + i);
    f32x4 gg = *(const f32x4*)(gw + i);
    f32x4 bb = *(const f32x4*)(bw + i);
    union { ushort_t u[4]; unsigned long long q; } o;
    o.u[0] = f2bf((v.x-mu)*rstd*gg.x + bb.x);
    o.u[1] = f2bf((v.y-mu)*rstd*gg.y + bb.y);
    o.u[2] = f2bf((v.z-mu)*rstd*gg.z + bb.z);
    o.u[3] = f2bf((v.w-mu)*rstd*gg.w + bb.w);
    *(unsigned long long*)(xo + i) = o.q;
  }
  if (t < (DINP - DIN)) xo[DIN + t] = 0;   // zero K-pad
}

// ---------------- transpose + cast fp32 [K,N] -> bf16 [N,Kp] ----------------
__global__ __launch_bounds__(256) void transpose_cast(const float* __restrict__ W,
                                                      ushort_t* __restrict__ WT,
                                                      int K, int Nn, int Kp){
  __shared__ float tile[32][33];
  const int tx = threadIdx.x & 31, ty = threadIdx.x >> 5;
  const int k0 = blockIdx.x*32, n0 = blockIdx.y*32;
  for (int i = ty; i < 32; i += 8){
    int k = k0 + i, n = n0 + tx;
    tile[i][tx] = (k < K && n < Nn) ? W[(size_t)k*Nn + n] : 0.f;
  }
  __syncthreads();
  for (int i = ty; i < 32; i += 8){
    int n = n0 + i, k = k0 + tx;
    if (n < Nn && k < Kp) WT[(size_t)n*Kp + k] = f2bf(tile[tx][i]);
  }
}

// ---------------- bf16 MFMA GEMM: C[M,Nn] = A[M,K] * BT[Nn,K]^T + bias ------
// MODE 0: f32 out. MODE 1: bf16 out. MODE 2: split (bcol<SPLITC -> f32 out0
// with bias; else bf16 out1, no bias, col-SPLITC). 1D grid, col-fastest
// logical order + bijective XCD-chunked swizzle (T1/m204).
template<int ACT, int MODE, int CB>
__global__ __launch_bounds__(256) void gemm_bt(const ushort_t* __restrict__ A,
                                               const ushort_t* __restrict__ BT,
                                               const float* __restrict__ bias,
                                               void* __restrict__ out0,
                                               void* __restrict__ out1,
                                               int M, int Nn, int K){
  __shared__ __align__(16) char smem[16384];
  ushort_t* lA = (ushort_t*)smem;           // 128x32 bf16 = 8KB
  ushort_t* lB = (ushort_t*)(smem + 8192);  // 128x32 bf16 = 8KB
  const int t = threadIdx.x, wid = t >> 6, lane = t & 63;

  // T1: XCD-chunked bijective swizzle. dispatch d -> XCD d%8 (round-robin);
  // give each XCD a contiguous chunk of the col-fastest logical space.
  const int bid = blockIdx.x, nwg = gridDim.x;
  const int q = nwg >> 3, r = nwg & 7;
  const int xcd = bid & 7, slot = bid >> 3;
  const int l = (xcd < r ? xcd*(q+1) : r*(q+1) + (xcd - r)*q) + slot;
  const int brow = (l / CB) * 128, bcol = (l % CB) * 128;

  const int r0 = wid*32 + (lane >> 2);
  int ar0 = brow + r0, ar1 = brow + r0 + 16;
  ar0 = ar0 < M ? ar0 : M-1;  ar1 = ar1 < M ? ar1 : M-1;
  int bb0 = bcol + r0, bb1 = bcol + r0 + 16;
  bb0 = bb0 < Nn ? bb0 : Nn-1; bb1 = bb1 < Nn ? bb1 : Nn-1;
  const int kc = (lane & 3)*8;
  const ushort_t* pa0 = A  + (size_t)ar0*K + kc;
  const ushort_t* pa1 = A  + (size_t)ar1*K + kc;
  const ushort_t* pb0 = BT + (size_t)bb0*K + kc;
  const ushort_t* pb1 = BT + (size_t)bb1*K + kc;
  ushort_t* la0 = &lA[(wid*32)*32];
  ushort_t* la1 = &lA[(wid*32+16)*32];
  ushort_t* lb0 = &lB[(wid*32)*32];
  ushort_t* lb1 = &lB[(wid*32+16)*32];

  f32x4 acc[4][4];
  #pragma unroll
  for (int i=0;i<4;i++)
    #pragma unroll
    for (int j=0;j<4;j++) acc[i][j] = (f32x4){0.f,0.f,0.f,0.f};

  const int wr = (wid >> 1)*64, wc = (wid & 1)*64;
  const int fo = (lane & 15)*32 + (lane >> 4)*8;   // fragment ds_read offset

  const int nk = K >> 5;
  for (int kt = 0; kt < nk; ++kt){
    async16(pa0, la0); async16(pa1, la1);
    async16(pb0, lb0); async16(pb1, lb1);
    pa0 += 32; pa1 += 32; pb0 += 32; pb1 += 32;
    __syncthreads();                 // drains vmcnt -> LDS tile visible
    short8 af[4], bfr[4];
    #pragma unroll
    for (int m=0;m<4;m++) af[m]  = *(const short8*)&lA[(wr + m*16)*32 + fo];
    #pragma unroll
    for (int n=0;n<4;n++) bfr[n] = *(const short8*)&lB[(wc + n*16)*32 + fo];
    #pragma unroll
    for (int m=0;m<4;m++)
      #pragma unroll
      for (int n=0;n<4;n++)
        acc[m][n] = __builtin_amdgcn_mfma_f32_16x16x32_bf16(af[m], bfr[n], acc[m][n], 0, 0, 0);
    __syncthreads();
  }

  // ---- epilogue: repack through LDS, coalesced stores, 4 chunks of 32 rows
  bool isf32;
  float* outF = nullptr; ushort_t* outB = nullptr; int ostride = 0, ocb = 0;
  if (MODE == 0){ isf32 = true;  outF = (float*)out0;    ostride = Nn; ocb = bcol; }
  else if (MODE == 1){ isf32 = false; outB = (ushort_t*)out0; ostride = Nn; ocb = bcol; }
  else {
    if (bcol < SPLITC){ isf32 = true;  outF = (float*)out0;    ostride = SPLITC;      ocb = bcol; }
    else              { isf32 = false; outB = (ushort_t*)out1; ostride = Nn - SPLITC; ocb = bcol - SPLITC; }
  }
  float bv[4];
  #pragma unroll
  for (int n=0;n<4;n++){
    const int col = wc + n*16 + (lane & 15);
    float b = 0.f;
    if (MODE == 2){ if (isf32 && bias) b = bias[bcol + col]; }
    else if (bias) b = bias[bcol + col];
    bv[n] = b;
  }
  float* sF = (float*)smem;
  ushort_t* sB = (ushort_t*)smem;
  const int trow = t >> 3, tc16 = (t & 7) * 16;
  #pragma unroll
  for (int c = 0; c < 4; ++c){
    __syncthreads();
    if ((wid >> 1) == (c >> 1)){
      #pragma unroll
      for (int mm = 0; mm < 2; ++mm){
        const int m = 2*(c & 1) + mm;
        const int rbase = m*16 + (lane >> 4)*4 - (c & 1)*32;   // 0..28
        #pragma unroll
        for (int n = 0; n < 4; ++n){
          const int col = wc + n*16 + (lane & 15);
          #pragma unroll
          for (int j = 0; j < 4; ++j){
            float v = acc[m][n][j] + bv[n];
            if (ACT) v = v > 0.f ? v : 0.f;
            if (isf32) sF[(rbase + j)*128 + col] = v;
            else       sB[(rbase + j)*128 + col] = f2bf(v);
          }
        }
      }
    }
    __syncthreads();
    const int grow = brow + c*32 + trow;
    if (grow < M){
      if (isf32){
        float* dst = outF + (size_t)grow*ostride + ocb + tc16;
        const float* src = sF + trow*128 + tc16;
        #pragma unroll
        for (int q2 = 0; q2 < 4; ++q2) ((f32x4*)dst)[q2] = ((const f32x4*)src)[q2];
      } else {
        ushort_t* dst = outB + (size_t)grow*ostride + ocb + tc16;
        const ushort_t* src = sB + trow*128 + tc16;
        #pragma unroll
        for (int q2 = 0; q2 < 2; ++q2) ((short8*)dst)[q2] = ((const short8*)src)[q2];
      }
    }
  }
}

// ---------------- attention scores a_src/a_dst: [N,8] = sum_c g*att --------
__global__ __launch_bounds__(256) void att_scores(const ushort_t* __restrict__ gm,
                                                  const float* __restrict__ att_s,
                                                  const float* __restrict__ att_d,
                                                  float* __restrict__ asrc,
                                                  float* __restrict__ adst){
  __shared__ float ss[256], sd[256];
  const int t = threadIdx.x;
  ss[t] = att_s[t]; sd[t] = att_d[t];
  __syncthreads();
  const int idx = blockIdx.x*256 + t;
  if (idx >= NND*NHD) return;
  const int n = idx >> 3, h = idx & 7;
  const ushort_t* gr = gm + (size_t)n*DHC + h*32;
  float a = 0.f, d = 0.f;
  #pragma unroll
  for (int c0 = 0; c0 < 32; c0 += 8){
    short8 gv = *(const short8*)(gr + c0);
    #pragma unroll
    for (int j = 0; j < 8; ++j){
      float g = bf2f((ushort_t)gv[j]);
      a += g*ss[h*32+c0+j]; d += g*sd[h*32+c0+j];
    }
  }
  asrc[idx] = a; adst[idx] = d;
}

// ---------------- CSR build ----------------
__global__ void init_cnt(int* cnt){
  int i = blockIdx.x*256 + threadIdx.x;
  if (i < NND) cnt[i] = 1;                       // self-loop
}
__global__ void count_edges(const int* __restrict__ ei, int* cnt){
  int e = blockIdx.x*256 + threadIdx.x;
  if (e < NE) atomicAdd(&cnt[ei[NE + e]], 1);
}
__global__ __launch_bounds__(1024) void scan_kernel(const int* __restrict__ cnt,
                                                    int* __restrict__ offs,
                                                    int* __restrict__ cur){
  __shared__ int buf[1024];
  const int t = threadIdx.x;
  const int chunk = (NND + 1023) >> 10;
  const int s0 = t*chunk, s1 = (s0 + chunk < NND) ? s0 + chunk : NND;
  int s = 0;
  for (int i = s0; i < s1; ++i) s += cnt[i];
  buf[t] = s; __syncthreads();
  for (int o = 1; o < 1024; o <<= 1){
    int x = (t >= o) ? buf[t-o] : 0;
    __syncthreads();
    buf[t] += x;
    __syncthreads();
  }
  int run = buf[t] - s;                          // exclusive prefix
  for (int i = s0; i < s1; ++i){
    int c = cnt[i];
    cur[i] = run;
    run += c;
    offs[i+1] = run;
  }
  if (t == 0) offs[0] = 0;
}
__global__ void fill_self(int* cur, int* eidx){
  int i = blockIdx.x*256 + threadIdx.x;
  if (i < NND){ int p = atomicAdd(&cur[i], 1); eidx[p] = i; }
}
__global__ void fill_edges(const int* __restrict__ ei, int* cur, int* eidx){
  int e = blockIdx.x*256 + threadIdx.x;
  if (e < NE){
    int src = ei[e], dst = ei[NE + e];
    int p = atomicAdd(&cur[dst], 1);
    eidx[p] = src;
  }
}

// ---------------- fused GAT aggregate + elu + residual (1 wave / node) -----
__global__ __launch_bounds__(256) void gat_agg(const int* __restrict__ offs,
                                               const int* __restrict__ eidx,
                                               const float* __restrict__ asrc,
                                               const float* __restrict__ adst,
                                               const ushort_t* __restrict__ gm,
                                               const float* __restrict__ res,
                                               const float* __restrict__ bg,
                                               float* __restrict__ out){
  const int wid = threadIdx.x >> 6, lane = threadIdx.x & 63;
  const int node = blockIdx.x*4 + wid;
  if (node >= NND) return;
  const int h = lane >> 3;
  const int e0 = offs[node], deg = offs[node+1] - e0;
  const float adv = adst[node*NHD + h];

  float mx = -1e30f;
  for (int j = (lane & 7); j < deg; j += 8){
    int s = eidx[e0 + j];
    float e = asrc[s*NHD + h] + adv; e = e > 0.f ? e : 0.2f*e;
    mx = fmaxf(mx, e);
  }
  mx = fmaxf(mx, __shfl_xor(mx, 1));
  mx = fmaxf(mx, __shfl_xor(mx, 2));
  mx = fmaxf(mx, __shfl_xor(mx, 4));

  float sm = 0.f;
  for (int j = (lane & 7); j < deg; j += 8){
    int s = eidx[e0 + j];
    float e = asrc[s*NHD + h] + adv; e = e > 0.f ? e : 0.2f*e;
    sm += __expf(e - mx);
  }
  sm += __shfl_xor(sm, 1); sm += __shfl_xor(sm, 2); sm += __shfl_xor(sm, 4);
  const float inv = 1.f/(sm + 1e-16f);

  const int c4 = lane*4;                          // channels [c4, c4+4) ; head c4/32 == h
  f32x4 acc = {0.f,0.f,0.f,0.f};
  for (int j = 0; j < deg; ++j){
    int s = eidx[e0 + j];
    float e = asrc[s*NHD + h] + adv; e = e > 0.f ? e : 0.2f*e;
    float w = __expf(e - mx)*inv;
    short4v gv = *(const short4v*)(gm + (size_t)s*DHC + c4);
    acc.x += w*bf2f((ushort_t)gv.x);
    acc.y += w*bf2f((ushort_t)gv.y);
    acc.z += w*bf2f((ushort_t)gv.z);
    acc.w += w*bf2f((ushort_t)gv.w);
  }
  f32x4 bgv = *(const f32x4*)(bg + c4);
  f32x4 rv  = *(const f32x4*)(res + (size_t)node*DHC + c4);
  f32x4 o;
  #pragma unroll
  for (int q = 0; q < 4; ++q){
    float v = acc[q] + bgv[q];
    v = v > 0.f ? v : expm1f(v);
    o[q] = v + rv[q];
  }
  *(f32x4*)(out + (size_t)node*DHC + c4) = o;
}

extern "C" void kernel_launch(void* const* d_in, const int* in_sizes, int n_in,
                              void* d_out, int out_size, void* d_ws, size_t ws_size,
                              hipStream_t stream){
  (void)in_sizes; (void)n_in; (void)out_size; (void)ws_size;
  const float* x     = (const float*)d_in[0];
  const int*   ei    = (const int*)d_in[1];          // int32 per harness convention
  const float* ln_g  = (const float*)d_in[2];
  const float* ln_b  = (const float*)d_in[3];
  const float* W1    = (const float*)d_in[4];
  const float* b1    = (const float*)d_in[5];
  const float* W2    = (const float*)d_in[6];
  const float* b2    = (const float*)d_in[7];
  const float* Wr    = (const float*)d_in[8];
  const float* br    = (const float*)d_in[9];
  const float* Wg    = (const float*)d_in[10];
  const float* att_s = (const float*)d_in[11];
  const float* att_d = (const float*)d_in[12];
  const float* bg    = (const float*)d_in[13];
  float* out = (float*)d_out;

  char* p = (char*)d_ws;
  // persistent region
  ushort_t* xn   = (ushort_t*)(p);                   // [0, 150,400,000)
  ushort_t* h1   = (ushort_t*)(p + 150400000);       // 102,400,000
  ushort_t* W1T  = (ushort_t*)(p + 252800000);       //   3,080,192
  ushort_t* W2T  = (ushort_t*)(p + 255880192);       //   1,048,576
  ushort_t* WrgT = (ushort_t*)(p + 256928768);       //     524,288 -> end 257,453,056
  // aliased into xn region (xn dead after gemm1)
  ushort_t* hb   = (ushort_t*)(p + 0);               //  51,200,000 (bf16)
  float*    res  = (float*)(p + 51200000);           //  51,200,000 (f32)
  ushort_t* gm   = (ushort_t*)(p + 102400000);       //  25,600,000 (bf16)
  float*    asrc = (float*)(p + 128000000);          //   1,600,000
  float*    adst = (float*)(p + 129600000);          //   1,600,000
  int*      cnt  = (int*)(p + 131200000);            //     200,000
  int*      offs = (int*)(p + 131400064);            //     200,004
  int*      cur  = (int*)(p + 131600128);            //     200,000
  int*      eidx = (int*)(p + 131800192);            //   3,400,000 -> end 135,200,192

  // weight prep (bf16, transposed, K-padded)
  transpose_cast<<<dim3(47,32), 256, 0, stream>>>(W1, W1T, DIN,  DHID, DINP);
  transpose_cast<<<dim3(32,16), 256, 0, stream>>>(W2, W2T, DHID, DOUT, DHID);
  transpose_cast<<<dim3(16, 8), 256, 0, stream>>>(Wr, WrgT,            DOUT, DHC, DOUT);
  transpose_cast<<<dim3(16, 8), 256, 0, stream>>>(Wg, WrgT + 256*DOUT, DOUT, DHC, DOUT);

  ln_kernel<<<NND, 256, 0, stream>>>(x, ln_g, ln_b, xn);

  gemm_bt<1,1,8><<<391*8, 256, 0, stream>>>(xn, W1T, b1, h1, nullptr, NND, DHID, DINP);
  gemm_bt<0,1,4><<<391*4, 256, 0, stream>>>(h1, W2T, b2, hb, nullptr, NND, DOUT, DHID);
  gemm_bt<0,2,4><<<391*4, 256, 0, stream>>>(hb, WrgT, br, res, gm, NND, 2*DHC, DOUT);

  att_scores<<<(NND*NHD + 255)/256, 256, 0, stream>>>(gm, att_s, att_d, asrc, adst);

  init_cnt<<<(NND + 255)/256, 256, 0, stream>>>(cnt);
  count_edges<<<(NE + 255)/256, 256, 0, stream>>>(ei, cnt);
  scan_kernel<<<1, 1024, 0, stream>>>(cnt, offs, cur);
  fill_self<<<(NND + 255)/256, 256, 0, stream>>>(cur, eidx);
  fill_edges<<<(NE + 255)/256, 256, 0, stream>>>(ei, cur, eidx);

  gat_agg<<<(NND + 3)/4, 256, 0, stream>>>(offs, eidx, asrc, adst, gm, res, bg, out);
}

// Round 5
// 776.210 us; speedup vs baseline: 1.2695x; 1.1872x over previous
//
#include <hip/hip_runtime.h>
#include <hip/hip_bf16.h>
#include <cstdint>
#include <cstddef>

#define NND 50000
#define DIN 1488
#define DINP 1536
#define DHID 1024
#define DOUT 512
#define DHC 256
#define NE 800000
#define NHD 8
#define SPLITC 256

typedef __attribute__((ext_vector_type(8))) short short8;
typedef __attribute__((ext_vector_type(4))) short short4v;
typedef __attribute__((ext_vector_type(4))) float f32x4;
typedef unsigned short ushort_t;

__device__ __forceinline__ unsigned short f2bf(float f){
  union { float f; unsigned u; } v; v.f = f;
  unsigned r = v.u + 0x7fffu + ((v.u >> 16) & 1u);
  return (unsigned short)(r >> 16);
}
__device__ __forceinline__ float bf2f(unsigned short u){
  union { unsigned u; float f; } v; v.u = ((unsigned)u) << 16;
  return v.f;
}

__device__ __forceinline__ void async16(const void* g, void* l){
  __builtin_amdgcn_global_load_lds((__attribute__((address_space(1))) void*)g,
                                   (__attribute__((address_space(3))) void*)l, 16, 0, 0);
}

// ---------------- LayerNorm (fp32 -> bf16, pad 1488 -> 1536) ----------------
__global__ __launch_bounds__(256) void ln_kernel(const float* __restrict__ x,
                                                 const float* __restrict__ gw,
                                                 const float* __restrict__ bw,
                                                 ushort_t* __restrict__ xn){
  const int row = blockIdx.x;
  const float* xr = x + (size_t)row * DIN;
  const int t = threadIdx.x;
  float s = 0.f, sq = 0.f;
  for (int i = t*4; i < DIN; i += 1024){
    f32x4 v = *(const f32x4*)(xr + i);
    s  += v.x + v.y + v.z + v.w;
    sq += v.x*v.x + v.y*v.y + v.z*v.z + v.w*v.w;
  }
  for (int o = 32; o; o >>= 1){ s += __shfl_xor(s, o); sq += __shfl_xor(sq, o); }
  __shared__ float rs[4], rq[4];
  const int wid = t >> 6, lane = t & 63;
  if (!lane){ rs[wid] = s; rq[wid] = sq; }
  __syncthreads();
  s = rs[0]+rs[1]+rs[2]+rs[3]; sq = rq[0]+rq[1]+rq[2]+rq[3];
  const float mu = s * (1.f/DIN);
  const float var = sq * (1.f/DIN) - mu*mu;
  const float rstd = rsqrtf(var + 1e-5f);
  ushort_t* xo = xn + (size_t)row * DINP;
  for (int i = t*4; i < DIN; i += 1024){
    f32x4 v = *(const f32x4*)(xr + i);
    f32x4 gg = *(const f32x4*)(gw + i);
    f32x4 bb = *(const f32x4*)(bw + i);
    union { ushort_t u[4]; unsigned long long q; } o;
    o.u[0] = f2bf((v.x-mu)*rstd*gg.x + bb.x);
    o.u[1] = f2bf((v.y-mu)*rstd*gg.y + bb.y);
    o.u[2] = f2bf((v.z-mu)*rstd*gg.z + bb.z);
    o.u[3] = f2bf((v.w-mu)*rstd*gg.w + bb.w);
    *(unsigned long long*)(xo + i) = o.q;
  }
  if (t < (DINP - DIN)) xo[DIN + t] = 0;   // zero K-pad (48 elems)
}

// ---------------- transpose + cast fp32 [K,N] -> bf16 [N,Kp] ----------------
__global__ __launch_bounds__(256) void transpose_cast(const float* __restrict__ W,
                                                      ushort_t* __restrict__ WT,
                                                      int K, int Nn, int Kp){
  __shared__ float tile[32][33];
  const int tx = threadIdx.x & 31, ty = threadIdx.x >> 5;
  const int k0 = blockIdx.x*32, n0 = blockIdx.y*32;
  for (int i = ty; i < 32; i += 8){
    int k = k0 + i, n = n0 + tx;
    tile[i][tx] = (k < K && n < Nn) ? W[(size_t)k*Nn + n] : 0.f;
  }
  __syncthreads();
  for (int i = ty; i < 32; i += 8){
    int n = n0 + i, k = k0 + tx;
    if (n < Nn && k < Kp) WT[(size_t)n*Kp + k] = f2bf(tile[tx][i]);
  }
}

// ---------------- pipelined bf16 MFMA GEMM (T1+T2+T3+T4+T5) -----------------
// C[M,Nn] = A[M,K] * BT[Nn,K]^T + bias. K multiple of 64 (nk>=2), Nn mult 128.
// BK=64, dbuf LDS 64KB, counted vmcnt(8), XOR-swizzled LDS (byte^=(row&7)<<4)
// via pre-swizzled global source + swizzled ds_read.
template<int ACT, int MODE, int CB>
__global__ __launch_bounds__(256, 2) void gemm_bt(const ushort_t* __restrict__ A,
                                                  const ushort_t* __restrict__ BT,
                                                  const float* __restrict__ bias,
                                                  void* __restrict__ out0,
                                                  void* __restrict__ out1,
                                                  int M, int Nn, int K){
  __shared__ __align__(16) ushort_t lds[2][2][128*64];   // [dbuf][A,B][128 rows x 64 k]
  const int t = threadIdx.x, wid = t >> 6, lane = t & 63;

  // T1: XCD-chunked bijective swizzle (m204)
  const int bid = blockIdx.x, nwg = gridDim.x;
  const int q = nwg >> 3, r = nwg & 7;
  const int xcd = bid & 7, slot = bid >> 3;
  const int lg = (xcd < r ? xcd*(q+1) : r*(q+1) + (xcd - r)*q) + slot;
  const int brow = (lg / CB) * 128, bcol = (lg % CB) * 128;

  // --- staging source addresses (pre-swizzled column so linear LDS write
  //     produces the swizzled layout) ---
  const int l8  = t >> 3;                  // row index within 32-row round
  const int cb  = (t & 7) << 4;            // LDS colbyte 0..112
  const int scb = cb ^ ((l8 & 7) << 4);    // inverse-swizzled source colbyte
  const ushort_t* pAr[4]; const ushort_t* pBr[4];
  #pragma unroll
  for (int rd = 0; rd < 4; ++rd){
    int ra = brow + rd*32 + l8; ra = ra < M ? ra : M-1;
    int rb = bcol + rd*32 + l8; rb = rb < Nn ? rb : Nn-1;
    pAr[rd] = A  + (size_t)ra*K + (scb >> 1);
    pBr[rd] = BT + (size_t)rb*K + (scb >> 1);
  }
  const int w8 = wid * 8;                  // wave's 8-row slice of each round

#define STAGE(buf, kt) do {                                            \
    const int _o = (kt) * 64;                                          \
    _Pragma("unroll")                                                  \
    for (int _rd = 0; _rd < 4; ++_rd){                                 \
      async16(pAr[_rd] + _o, &lds[buf][0][(_rd*32 + w8)*64]);          \
      async16(pBr[_rd] + _o, &lds[buf][1][(_rd*32 + w8)*64]);          \
    }                                                                  \
  } while(0)

  f32x4 acc[4][4];
  #pragma unroll
  for (int i=0;i<4;i++)
    #pragma unroll
    for (int j=0;j<4;j++) acc[i][j] = (f32x4){0.f,0.f,0.f,0.f};

  const int wr = (wid >> 1)*64, wc = (wid & 1)*64;
  const int fr = lane & 15;
  const int kb0 = (lane >> 4) << 4;        // 0,16,32,48 bytes
  const int sx  = (fr & 7) << 4;           // read-side swizzle (row&7 == fr&7)
  const int ko0 = ((kb0      ) ^ sx) >> 1; // element k-offset, ks=0
  const int ko1 = ((kb0 | 64 ) ^ sx) >> 1; // element k-offset, ks=1

  const int nk = K >> 6;
  STAGE(0, 0);
  STAGE(1, 1);
  for (int kt = 0; kt < nk; ++kt){
    const ushort_t* bA = lds[kt & 1][0];
    const ushort_t* bB = lds[kt & 1][1];
    if (kt + 1 < nk) asm volatile("s_waitcnt vmcnt(8)" ::: "memory");
    else             asm volatile("s_waitcnt vmcnt(0)" ::: "memory");
    __builtin_amdgcn_s_barrier();
    short8 af[4][2], bf_[4][2];
    #pragma unroll
    for (int m=0;m<4;m++){
      const int ra = (wr + m*16 + fr)*64;
      const int rb = (wc + m*16 + fr)*64;
      af[m][0]  = *(const short8*)&bA[ra + ko0];
      af[m][1]  = *(const short8*)&bA[ra + ko1];
      bf_[m][0] = *(const short8*)&bB[rb + ko0];
      bf_[m][1] = *(const short8*)&bB[rb + ko1];
    }
    asm volatile("s_waitcnt lgkmcnt(0)" ::: "memory");
    __builtin_amdgcn_sched_barrier(0);
    __builtin_amdgcn_s_barrier();
    if (kt + 2 < nk) STAGE(kt & 1, kt + 2);
    __builtin_amdgcn_s_setprio(1);
    #pragma unroll
    for (int m=0;m<4;m++)
      #pragma unroll
      for (int n=0;n<4;n++){
        acc[m][n] = __builtin_amdgcn_mfma_f32_16x16x32_bf16(af[m][0], bf_[n][0], acc[m][n], 0, 0, 0);
        acc[m][n] = __builtin_amdgcn_mfma_f32_16x16x32_bf16(af[m][1], bf_[n][1], acc[m][n], 0, 0, 0);
      }
    __builtin_amdgcn_s_setprio(0);
  }
#undef STAGE

  // ---- epilogue: repack through LDS, coalesced stores, 4 chunks of 32 rows
  bool isf32;
  float* outF = nullptr; ushort_t* outB = nullptr; int ostride = 0, ocb = 0;
  if (MODE == 0){ isf32 = true;  outF = (float*)out0;    ostride = Nn; ocb = bcol; }
  else if (MODE == 1){ isf32 = false; outB = (ushort_t*)out0; ostride = Nn; ocb = bcol; }
  else {
    if (bcol < SPLITC){ isf32 = true;  outF = (float*)out0;    ostride = SPLITC;      ocb = bcol; }
    else              { isf32 = false; outB = (ushort_t*)out1; ostride = Nn - SPLITC; ocb = bcol - SPLITC; }
  }
  float bv[4];
  #pragma unroll
  for (int n=0;n<4;n++){
    const int col = wc + n*16 + (lane & 15);
    float b = 0.f;
    if (MODE == 2){ if (isf32 && bias) b = bias[bcol + col]; }
    else if (bias) b = bias[bcol + col];
    bv[n] = b;
  }
  float* sF = (float*)&lds[0][0][0];
  ushort_t* sB = (ushort_t*)&lds[0][0][0];
  const int trow = t >> 3, tc16 = (t & 7) * 16;
  #pragma unroll
  for (int c = 0; c < 4; ++c){
    __syncthreads();
    if ((wid >> 1) == (c >> 1)){
      #pragma unroll
      for (int mm = 0; mm < 2; ++mm){
        const int m = 2*(c & 1) + mm;
        const int rbase = m*16 + (lane >> 4)*4 - (c & 1)*32;   // 0..28
        #pragma unroll
        for (int n = 0; n < 4; ++n){
          const int col = wc + n*16 + (lane & 15);
          #pragma unroll
          for (int j = 0; j < 4; ++j){
            float v = acc[m][n][j] + bv[n];
            if (ACT) v = v > 0.f ? v : 0.f;
            if (isf32) sF[(rbase + j)*128 + col] = v;
            else       sB[(rbase + j)*128 + col] = f2bf(v);
          }
        }
      }
    }
    __syncthreads();
    const int grow = brow + c*32 + trow;
    if (grow < M){
      if (isf32){
        float* dst = outF + (size_t)grow*ostride + ocb + tc16;
        const float* src = sF + trow*128 + tc16;
        #pragma unroll
        for (int q2 = 0; q2 < 4; ++q2) ((f32x4*)dst)[q2] = ((const f32x4*)src)[q2];
      } else {
        ushort_t* dst = outB + (size_t)grow*ostride + ocb + tc16;
        const ushort_t* src = sB + trow*128 + tc16;
        #pragma unroll
        for (int q2 = 0; q2 < 2; ++q2) ((short8*)dst)[q2] = ((const short8*)src)[q2];
      }
    }
  }
}

// ---------------- attention scores a_src/a_dst: [N,8] = sum_c g*att --------
__global__ __launch_bounds__(256) void att_scores(const ushort_t* __restrict__ gm,
                                                  const float* __restrict__ att_s,
                                                  const float* __restrict__ att_d,
                                                  float* __restrict__ asrc,
                                                  float* __restrict__ adst){
  __shared__ float ss[256], sd[256];
  const int t = threadIdx.x;
  ss[t] = att_s[t]; sd[t] = att_d[t];
  __syncthreads();
  const int idx = blockIdx.x*256 + t;
  if (idx >= NND*NHD) return;
  const int n = idx >> 3, h = idx & 7;
  const ushort_t* gr = gm + (size_t)n*DHC + h*32;
  float a = 0.f, d = 0.f;
  #pragma unroll
  for (int c0 = 0; c0 < 32; c0 += 8){
    short8 gv = *(const short8*)(gr + c0);
    #pragma unroll
    for (int j = 0; j < 8; ++j){
      float g = bf2f((ushort_t)gv[j]);
      a += g*ss[h*32+c0+j]; d += g*sd[h*32+c0+j];
    }
  }
  asrc[idx] = a; adst[idx] = d;
}

// ---------------- CSR build ----------------
__global__ void init_cnt(int* cnt){
  int i = blockIdx.x*256 + threadIdx.x;
  if (i < NND) cnt[i] = 1;                       // self-loop
}
__global__ void count_edges(const int* __restrict__ ei, int* cnt){
  int e = blockIdx.x*256 + threadIdx.x;
  if (e < NE) atomicAdd(&cnt[ei[NE + e]], 1);
}
__global__ __launch_bounds__(1024) void scan_kernel(const int* __restrict__ cnt,
                                                    int* __restrict__ offs,
                                                    int* __restrict__ cur){
  __shared__ int buf[1024];
  const int t = threadIdx.x;
  const int chunk = (NND + 1023) >> 10;
  const int s0 = t*chunk, s1 = (s0 + chunk < NND) ? s0 + chunk : NND;
  int s = 0;
  for (int i = s0; i < s1; ++i) s += cnt[i];
  buf[t] = s; __syncthreads();
  for (int o = 1; o < 1024; o <<= 1){
    int x = (t >= o) ? buf[t-o] : 0;
    __syncthreads();
    buf[t] += x;
    __syncthreads();
  }
  int run = buf[t] - s;                          // exclusive prefix
  for (int i = s0; i < s1; ++i){
    int c = cnt[i];
    cur[i] = run;
    run += c;
    offs[i+1] = run;
  }
  if (t == 0) offs[0] = 0;
}
__global__ void fill_self(int* cur, int* eidx){
  int i = blockIdx.x*256 + threadIdx.x;
  if (i < NND){ int p = atomicAdd(&cur[i], 1); eidx[p] = i; }
}
__global__ void fill_edges(const int* __restrict__ ei, int* cur, int* eidx){
  int e = blockIdx.x*256 + threadIdx.x;
  if (e < NE){
    int src = ei[e], dst = ei[NE + e];
    int p = atomicAdd(&cur[dst], 1);
    eidx[p] = src;
  }
}

// ---------------- fused GAT aggregate + elu + residual (1 wave / node) -----
__global__ __launch_bounds__(256) void gat_agg(const int* __restrict__ offs,
                                               const int* __restrict__ eidx,
                                               const float* __restrict__ asrc,
                                               const float* __restrict__ adst,
                                               const ushort_t* __restrict__ gm,
                                               const float* __restrict__ res,
                                               const float* __restrict__ bg,
                                               float* __restrict__ out){
  const int wid = threadIdx.x >> 6, lane = threadIdx.x & 63;
  const int node = blockIdx.x*4 + wid;
  if (node >= NND) return;
  const int h = lane >> 3;
  const int e0 = offs[node], deg = offs[node+1] - e0;
  const float adv = adst[node*NHD + h];

  float mx = -1e30f;
  for (int j = (lane & 7); j < deg; j += 8){
    int s = eidx[e0 + j];
    float e = asrc[s*NHD + h] + adv; e = e > 0.f ? e : 0.2f*e;
    mx = fmaxf(mx, e);
  }
  mx = fmaxf(mx, __shfl_xor(mx, 1));
  mx = fmaxf(mx, __shfl_xor(mx, 2));
  mx = fmaxf(mx, __shfl_xor(mx, 4));

  float sm = 0.f;
  for (int j = (lane & 7); j < deg; j += 8){
    int s = eidx[e0 + j];
    float e = asrc[s*NHD + h] + adv; e = e > 0.f ? e : 0.2f*e;
    sm += __expf(e - mx);
  }
  sm += __shfl_xor(sm, 1); sm += __shfl_xor(sm, 2); sm += __shfl_xor(sm, 4);
  const float inv = 1.f/(sm + 1e-16f);

  const int c4 = lane*4;                          // channels [c4, c4+4) ; head c4/32 == h
  f32x4 acc = {0.f,0.f,0.f,0.f};
  for (int j = 0; j < deg; ++j){
    int s = eidx[e0 + j];
    float e = asrc[s*NHD + h] + adv; e = e > 0.f ? e : 0.2f*e;
    float w = __expf(e - mx)*inv;
    short4v gv = *(const short4v*)(gm + (size_t)s*DHC + c4);
    acc.x += w*bf2f((ushort_t)gv.x);
    acc.y += w*bf2f((ushort_t)gv.y);
    acc.z += w*bf2f((ushort_t)gv.z);
    acc.w += w*bf2f((ushort_t)gv.w);
  }
  f32x4 bgv = *(const f32x4*)(bg + c4);
  f32x4 rv  = *(const f32x4*)(res + (size_t)node*DHC + c4);
  f32x4 o;
  #pragma unroll
  for (int q = 0; q < 4; ++q){
    float v = acc[q] + bgv[q];
    v = v > 0.f ? v : expm1f(v);
    o[q] = v + rv[q];
  }
  *(f32x4*)(out + (size_t)node*DHC + c4) = o;
}

extern "C" void kernel_launch(void* const* d_in, const int* in_sizes, int n_in,
                              void* d_out, int out_size, void* d_ws, size_t ws_size,
                              hipStream_t stream){
  (void)in_sizes; (void)n_in; (void)out_size; (void)ws_size;
  const float* x     = (const float*)d_in[0];
  const int*   ei    = (const int*)d_in[1];          // int32 per harness convention
  const float* ln_g  = (const float*)d_in[2];
  const float* ln_b  = (const float*)d_in[3];
  const float* W1    = (const float*)d_in[4];
  const float* b1    = (const float*)d_in[5];
  const float* W2    = (const float*)d_in[6];
  const float* b2    = (const float*)d_in[7];
  const float* Wr    = (const float*)d_in[8];
  const float* br    = (const float*)d_in[9];
  const float* Wg    = (const float*)d_in[10];
  const float* att_s = (const float*)d_in[11];
  const float* att_d = (const float*)d_in[12];
  const float* bg    = (const float*)d_in[13];
  float* out = (float*)d_out;

  char* p = (char*)d_ws;
  // persistent region (ws): xn 153.6MB + h1 102.4MB = 256.0MB
  ushort_t* xn   = (ushort_t*)(p);                   // [0, 153,600,000)
  ushort_t* h1   = (ushort_t*)(p + 153600000);       // 102,400,000 -> 256,000,000
  // transposed weights live in d_out (dead until gat_agg overwrites all of it)
  ushort_t* W1T  = (ushort_t*)d_out;                           // 3,145,728
  ushort_t* W2T  = (ushort_t*)((char*)d_out + 3145728);        // 1,048,576
  ushort_t* WrgT = (ushort_t*)((char*)d_out + 4194304);        //   524,288 -> 4,718,592
  // aliased into xn region (xn dead after gemm1)
  ushort_t* hb   = (ushort_t*)(p + 0);               //  51,200,000 (bf16)
  float*    res  = (float*)(p + 51200000);           //  51,200,000 (f32)
  ushort_t* gm   = (ushort_t*)(p + 102400000);       //  25,600,000 (bf16)
  float*    asrc = (float*)(p + 128000000);          //   1,600,000
  float*    adst = (float*)(p + 129600000);          //   1,600,000
  int*      cnt  = (int*)(p + 131200000);            //     200,000
  int*      offs = (int*)(p + 131400064);            //     200,004
  int*      cur  = (int*)(p + 131600128);            //     200,000
  int*      eidx = (int*)(p + 131800192);            //   3,400,000 -> end 135,200,192

  // weight prep (bf16, transposed, K-padded)
  transpose_cast<<<dim3(48,32), 256, 0, stream>>>(W1, W1T, DIN,  DHID, DINP);
  transpose_cast<<<dim3(32,16), 256, 0, stream>>>(W2, W2T, DHID, DOUT, DHID);
  transpose_cast<<<dim3(16, 8), 256, 0, stream>>>(Wr, WrgT,            DOUT, DHC, DOUT);
  transpose_cast<<<dim3(16, 8), 256, 0, stream>>>(Wg, WrgT + 256*DOUT, DOUT, DHC, DOUT);

  ln_kernel<<<NND, 256, 0, stream>>>(x, ln_g, ln_b, xn);

  gemm_bt<1,1,8><<<391*8, 256, 0, stream>>>(xn, W1T, b1, h1, nullptr, NND, DHID, DINP);
  gemm_bt<0,1,4><<<391*4, 256, 0, stream>>>(h1, W2T, b2, hb, nullptr, NND, DOUT, DHID);
  gemm_bt<0,2,4><<<391*4, 256, 0, stream>>>(hb, WrgT, br, res, gm, NND, 2*DHC, DOUT);

  att_scores<<<(NND*NHD + 255)/256, 256, 0, stream>>>(gm, att_s, att_d, asrc, adst);

  init_cnt<<<(NND + 255)/256, 256, 0, stream>>>(cnt);
  count_edges<<<(NE + 255)/256, 256, 0, stream>>>(ei, cnt);
  scan_kernel<<<1, 1024, 0, stream>>>(cnt, offs, cur);
  fill_self<<<(NND + 255)/256, 256, 0, stream>>>(cur, eidx);
  fill_edges<<<(NE + 255)/256, 256, 0, stream>>>(ei, cur, eidx);

  gat_agg<<<(NND + 3)/4, 256, 0, stream>>>(offs, eidx, asrc, adst, gm, res, bg, out);
}

// Round 6
// 756.912 us; speedup vs baseline: 1.3018x; 1.0255x over previous
//
#include <hip/hip_runtime.h>
#include <hip/hip_bf16.h>
#include <cstdint>
#include <cstddef>

#define NND 50000
#define DIN 1488
#define DINP 1536
#define DHID 1024
#define DOUT 512
#define DHC 256
#define NE 800000
#define NHD 8

typedef __attribute__((ext_vector_type(8))) short short8;
typedef __attribute__((ext_vector_type(4))) short short4v;
typedef __attribute__((ext_vector_type(4))) float f32x4;
typedef unsigned short ushort_t;

__device__ __forceinline__ unsigned short f2bf(float f){
  union { float f; unsigned u; } v; v.f = f;
  unsigned r = v.u + 0x7fffu + ((v.u >> 16) & 1u);
  return (unsigned short)(r >> 16);
}
__device__ __forceinline__ float bf2f(unsigned short u){
  union { unsigned u; float f; } v; v.u = ((unsigned)u) << 16;
  return v.f;
}

__device__ __forceinline__ void async16(const void* g, void* l){
  __builtin_amdgcn_global_load_lds((__attribute__((address_space(1))) void*)g,
                                   (__attribute__((address_space(3))) void*)l, 16, 0, 0);
}

// ---------------- LayerNorm (fp32 -> bf16, pad 1488 -> 1536) ----------------
__global__ __launch_bounds__(256) void ln_kernel(const float* __restrict__ x,
                                                 const float* __restrict__ gw,
                                                 const float* __restrict__ bw,
                                                 ushort_t* __restrict__ xn){
  const int row = blockIdx.x;
  const float* xr = x + (size_t)row * DIN;
  const int t = threadIdx.x;
  float s = 0.f, sq = 0.f;
  for (int i = t*4; i < DIN; i += 1024){
    f32x4 v = *(const f32x4*)(xr + i);
    s  += v.x + v.y + v.z + v.w;
    sq += v.x*v.x + v.y*v.y + v.z*v.z + v.w*v.w;
  }
  for (int o = 32; o; o >>= 1){ s += __shfl_xor(s, o); sq += __shfl_xor(sq, o); }
  __shared__ float rs[4], rq[4];
  const int wid = t >> 6, lane = t & 63;
  if (!lane){ rs[wid] = s; rq[wid] = sq; }
  __syncthreads();
  s = rs[0]+rs[1]+rs[2]+rs[3]; sq = rq[0]+rq[1]+rq[2]+rq[3];
  const float mu = s * (1.f/DIN);
  const float var = sq * (1.f/DIN) - mu*mu;
  const float rstd = rsqrtf(var + 1e-5f);
  ushort_t* xo = xn + (size_t)row * DINP;
  for (int i = t*4; i < DIN; i += 1024){
    f32x4 v = *(const f32x4*)(xr + i);
    f32x4 gg = *(const f32x4*)(gw + i);
    f32x4 bb = *(const f32x4*)(bw + i);
    union { ushort_t u[4]; unsigned long long q; } o;
    o.u[0] = f2bf((v.x-mu)*rstd*gg.x + bb.x);
    o.u[1] = f2bf((v.y-mu)*rstd*gg.y + bb.y);
    o.u[2] = f2bf((v.z-mu)*rstd*gg.z + bb.z);
    o.u[3] = f2bf((v.w-mu)*rstd*gg.w + bb.w);
    *(unsigned long long*)(xo + i) = o.q;
  }
  if (t < (DINP - DIN)) xo[DIN + t] = 0;   // zero K-pad (48 elems)
}

// ---------------- transpose + cast fp32 [K,N] -> bf16 [N,Kp] ----------------
__global__ __launch_bounds__(256) void transpose_cast(const float* __restrict__ W,
                                                      ushort_t* __restrict__ WT,
                                                      int K, int Nn, int Kp){
  __shared__ float tile[32][33];
  const int tx = threadIdx.x & 31, ty = threadIdx.x >> 5;
  const int k0 = blockIdx.x*32, n0 = blockIdx.y*32;
  for (int i = ty; i < 32; i += 8){
    int k = k0 + i, n = n0 + tx;
    tile[i][tx] = (k < K && n < Nn) ? W[(size_t)k*Nn + n] : 0.f;
  }
  __syncthreads();
  for (int i = ty; i < 32; i += 8){
    int n = n0 + i, k = k0 + tx;
    if (n < Nn && k < Kp) WT[(size_t)n*Kp + k] = f2bf(tile[tx][i]);
  }
}

// ------------- pipelined 256x256 bf16 MFMA GEMM (T1+T2+T3+T4+T5) -----------
// C[M,Nn] = A[M,K]*BT[Nn,K]^T + bias. K mult 64, Nn mult 256, M row-clamped.
// 512 threads = 8 waves (2Mx4N), BK=64, 128KB dbuf LDS, counted vmcnt(8),
// both-sides XOR swizzle (byte ^= (row&7)<<4). Same sync structure as the
// verified 128^2 loop (parameter scale-up only).
// MODE 0: f32 out0 (stride Nn). MODE 1: bf16 out0 (stride Nn).
// MODE 2: block-level split: bcol==0 -> f32 out0 (stride 256, bias);
//                            bcol==256 -> bf16 out1 (stride 256, no bias).
template<int ACT, int MODE, int CB>
__global__ __launch_bounds__(512, 2) void gemm_bt(const ushort_t* __restrict__ A,
                                                  const ushort_t* __restrict__ BT,
                                                  const float* __restrict__ bias,
                                                  void* __restrict__ out0,
                                                  void* __restrict__ out1,
                                                  int M, int Nn, int K){
  __shared__ __align__(16) ushort_t lds[2][2][256*64];   // 128 KiB
  const int t = threadIdx.x, wid = t >> 6, lane = t & 63;

  // T1: XCD-chunked bijective swizzle (m204)
  const int bid = blockIdx.x, nwg = gridDim.x;
  const int q = nwg >> 3, r = nwg & 7;
  const int xcd = bid & 7, slot = bid >> 3;
  const int lg = (xcd < r ? xcd*(q+1) : r*(q+1) + (xcd - r)*q) + slot;
  const int brow = (lg / CB) * 256, bcol = (lg % CB) * 256;

  // staging: thread t covers LDS row (rd*64 + (t>>3)), colbyte (t&7)*16,
  // source column pre-swizzled so linear LDS write lands swizzled.
  const int l8  = t >> 3;
  const int cb  = (t & 7) << 4;
  const unsigned scb = (unsigned)(cb ^ ((l8 & 7) << 4));
  unsigned rowA[4], rowB[4];
  #pragma unroll
  for (int rd = 0; rd < 4; ++rd){
    int ra = brow + rd*64 + l8; ra = ra < M ? ra : M-1;
    int rb = bcol + rd*64 + l8; rb = rb < Nn ? rb : Nn-1;
    rowA[rd] = (unsigned)ra * (unsigned)(K*2);
    rowB[rd] = (unsigned)rb * (unsigned)(K*2);
  }
  const int wst = (wid * 8) * 64;          // wave LDS elem base per round

#define STAGE(buf, kt) do {                                               \
    const unsigned _ob = (unsigned)(kt)*128u + scb;                       \
    _Pragma("unroll")                                                     \
    for (int _rd = 0; _rd < 4; ++_rd){                                    \
      async16((const char*)A  + rowA[_rd] + _ob, &lds[buf][0][_rd*64*64 + wst]); \
      async16((const char*)BT + rowB[_rd] + _ob, &lds[buf][1][_rd*64*64 + wst]); \
    }                                                                     \
  } while(0)

  f32x4 acc[8][4];
  #pragma unroll
  for (int i=0;i<8;i++)
    #pragma unroll
    for (int j=0;j<4;j++) acc[i][j] = (f32x4){0.f,0.f,0.f,0.f};

  const int wrow = (wid >> 2), wcol = (wid & 3);   // 2 x 4 waves
  const int fr = lane & 15;
  const int kb0 = (lane >> 4) << 4;        // 0,16,32,48 bytes
  const int sx  = (fr & 7) << 4;           // read-side swizzle
  const int ko0 = ((kb0      ) ^ sx) >> 1;
  const int ko1 = ((kb0 | 64 ) ^ sx) >> 1;

  const int nk = K >> 6;
  STAGE(0, 0);
  STAGE(1, 1);
  for (int kt = 0; kt < nk; ++kt){
    const ushort_t* bA = lds[kt & 1][0];
    const ushort_t* bB = lds[kt & 1][1];
    if (kt + 1 < nk) asm volatile("s_waitcnt vmcnt(8)" ::: "memory");
    else             asm volatile("s_waitcnt vmcnt(0)" ::: "memory");
    __builtin_amdgcn_s_barrier();
    short8 af[8][2], bf_[4][2];
    #pragma unroll
    for (int m=0;m<8;m++){
      const int ra = (wrow*128 + m*16 + fr)*64;
      af[m][0] = *(const short8*)&bA[ra + ko0];
      af[m][1] = *(const short8*)&bA[ra + ko1];
    }
    #pragma unroll
    for (int n=0;n<4;n++){
      const int rb = (wcol*64 + n*16 + fr)*64;
      bf_[n][0] = *(const short8*)&bB[rb + ko0];
      bf_[n][1] = *(const short8*)&bB[rb + ko1];
    }
    asm volatile("s_waitcnt lgkmcnt(0)" ::: "memory");
    __builtin_amdgcn_sched_barrier(0);
    __builtin_amdgcn_s_barrier();
    if (kt + 2 < nk) STAGE(kt & 1, kt + 2);
    __builtin_amdgcn_s_setprio(1);
    #pragma unroll
    for (int m=0;m<8;m++)
      #pragma unroll
      for (int n=0;n<4;n++){
        acc[m][n] = __builtin_amdgcn_mfma_f32_16x16x32_bf16(af[m][0], bf_[n][0], acc[m][n], 0, 0, 0);
        acc[m][n] = __builtin_amdgcn_mfma_f32_16x16x32_bf16(af[m][1], bf_[n][1], acc[m][n], 0, 0, 0);
      }
    __builtin_amdgcn_s_setprio(0);
  }
#undef STAGE

  // ---- epilogue: repack through 128KB LDS, coalesced 512B-row stores ----
  const bool isf32 = (MODE == 0) || (MODE == 2 && bcol == 0);
  float bv[4];
  #pragma unroll
  for (int n=0;n<4;n++){
    const int col = bcol + wcol*64 + n*16 + (lane & 15);
    float b = 0.f;
    if (MODE == 1){ if (bias) b = bias[col]; }
    if (MODE == 2){ if (isf32) b = bias[col]; }
    bv[n] = b;
  }

  if (isf32){
    float* outF; int ostride, ocb;
    if (MODE == 0){ outF = (float*)out0; ostride = Nn;  ocb = bcol; }
    else          { outF = (float*)out0; ostride = 256; ocb = 0;    }
    float* sF = (float*)&lds[0][0][0];                 // [128][256] f32
    #pragma unroll
    for (int p = 0; p < 2; ++p){
      __syncthreads();
      if (wrow == p){
        #pragma unroll
        for (int m=0;m<8;m++){
          const int row = m*16 + (lane >> 4)*4;
          #pragma unroll
          for (int n=0;n<4;n++){
            const int col = wcol*64 + n*16 + (lane & 15);
            #pragma unroll
            for (int j=0;j<4;j++){
              float v = acc[m][n][j] + bv[n];
              if (ACT) v = v > 0.f ? v : 0.f;
              sF[(row+j)*256 + col] = v;
            }
          }
        }
      }
      __syncthreads();
      const int srow = t >> 6, scol4 = (t & 63) * 4;
      #pragma unroll
      for (int rr = 0; rr < 16; ++rr){
        const int rloc = rr*8 + srow;
        const int grow = brow + p*128 + rloc;
        if (grow < M)
          *(f32x4*)(outF + (size_t)grow*ostride + ocb + scol4) = *(const f32x4*)&sF[rloc*256 + scol4];
      }
    }
  } else {
    ushort_t* outB; int ostride, ocb;
    if (MODE == 1){ outB = (ushort_t*)out0; ostride = Nn;  ocb = bcol; }
    else          { outB = (ushort_t*)out1; ostride = 256; ocb = 0;    }
    ushort_t* sB = (ushort_t*)&lds[0][0][0];           // [256][256] bf16
    __syncthreads();
    #pragma unroll
    for (int m=0;m<8;m++){
      const int row = wrow*128 + m*16 + (lane >> 4)*4;
      #pragma unroll
      for (int n=0;n<4;n++){
        const int col = wcol*64 + n*16 + (lane & 15);
        #pragma unroll
        for (int j=0;j<4;j++){
          float v = acc[m][n][j] + bv[n];
          if (ACT) v = v > 0.f ? v : 0.f;
          sB[(row+j)*256 + col] = f2bf(v);
        }
      }
    }
    __syncthreads();
    const int srow = t >> 5, scol8 = (t & 31) * 8;
    #pragma unroll
    for (int rr = 0; rr < 16; ++rr){
      const int rloc = rr*16 + srow;
      const int grow = brow + rloc;
      if (grow < M)
        *(short8*)(outB + (size_t)grow*ostride + ocb + scol8) = *(const short8*)&sB[rloc*256 + scol8];
    }
  }
}

// ---------------- attention scores a_src/a_dst: [N,8] = sum_c g*att --------
__global__ __launch_bounds__(256) void att_scores(const ushort_t* __restrict__ gm,
                                                  const float* __restrict__ att_s,
                                                  const float* __restrict__ att_d,
                                                  float* __restrict__ asrc,
                                                  float* __restrict__ adst){
  __shared__ float ss[256], sd[256];
  const int t = threadIdx.x;
  ss[t] = att_s[t]; sd[t] = att_d[t];
  __syncthreads();
  const int idx = blockIdx.x*256 + t;
  if (idx >= NND*NHD) return;
  const int n = idx >> 3, h = idx & 7;
  const ushort_t* gr = gm + (size_t)n*DHC + h*32;
  float a = 0.f, d = 0.f;
  #pragma unroll
  for (int c0 = 0; c0 < 32; c0 += 8){
    short8 gv = *(const short8*)(gr + c0);
    #pragma unroll
    for (int j = 0; j < 8; ++j){
      float g = bf2f((ushort_t)gv[j]);
      a += g*ss[h*32+c0+j]; d += g*sd[h*32+c0+j];
    }
  }
  asrc[idx] = a; adst[idx] = d;
}

// ---------------- CSR build ----------------
__global__ void init_cnt(int* cnt){
  int i = blockIdx.x*256 + threadIdx.x;
  if (i < NND) cnt[i] = 1;                       // self-loop
}
__global__ void count_edges(const int* __restrict__ ei, int* cnt){
  int e = blockIdx.x*256 + threadIdx.x;
  if (e < NE) atomicAdd(&cnt[ei[NE + e]], 1);
}
__global__ __launch_bounds__(1024) void scan_kernel(const int* __restrict__ cnt,
                                                    int* __restrict__ offs,
                                                    int* __restrict__ cur){
  __shared__ int buf[1024];
  const int t = threadIdx.x;
  const int chunk = (NND + 1023) >> 10;
  const int s0 = t*chunk, s1 = (s0 + chunk < NND) ? s0 + chunk : NND;
  int s = 0;
  for (int i = s0; i < s1; ++i) s += cnt[i];
  buf[t] = s; __syncthreads();
  for (int o = 1; o < 1024; o <<= 1){
    int x = (t >= o) ? buf[t-o] : 0;
    __syncthreads();
    buf[t] += x;
    __syncthreads();
  }
  int run = buf[t] - s;                          // exclusive prefix
  for (int i = s0; i < s1; ++i){
    int c = cnt[i];
    cur[i] = run;
    run += c;
    offs[i+1] = run;
  }
  if (t == 0) offs[0] = 0;
}
__global__ void fill_self(int* cur, int* eidx){
  int i = blockIdx.x*256 + threadIdx.x;
  if (i < NND){ int p = atomicAdd(&cur[i], 1); eidx[p] = i; }
}
__global__ void fill_edges(const int* __restrict__ ei, int* cur, int* eidx){
  int e = blockIdx.x*256 + threadIdx.x;
  if (e < NE){
    int src = ei[e], dst = ei[NE + e];
    int p = atomicAdd(&cur[dst], 1);
    eidx[p] = src;
  }
}

// ---------------- fused GAT aggregate + elu + residual (1 wave / node) -----
__global__ __launch_bounds__(256) void gat_agg(const int* __restrict__ offs,
                                               const int* __restrict__ eidx,
                                               const float* __restrict__ asrc,
                                               const float* __restrict__ adst,
                                               const ushort_t* __restrict__ gm,
                                               const float* __restrict__ res,
                                               const float* __restrict__ bg,
                                               float* __restrict__ out){
  const int wid = threadIdx.x >> 6, lane = threadIdx.x & 63;
  const int node = blockIdx.x*4 + wid;
  if (node >= NND) return;
  const int h = lane >> 3;
  const int e0 = offs[node], deg = offs[node+1] - e0;
  const float adv = adst[node*NHD + h];

  float mx = -1e30f;
  for (int j = (lane & 7); j < deg; j += 8){
    int s = eidx[e0 + j];
    float e = asrc[s*NHD + h] + adv; e = e > 0.f ? e : 0.2f*e;
    mx = fmaxf(mx, e);
  }
  mx = fmaxf(mx, __shfl_xor(mx, 1));
  mx = fmaxf(mx, __shfl_xor(mx, 2));
  mx = fmaxf(mx, __shfl_xor(mx, 4));

  float sm = 0.f;
  for (int j = (lane & 7); j < deg; j += 8){
    int s = eidx[e0 + j];
    float e = asrc[s*NHD + h] + adv; e = e > 0.f ? e : 0.2f*e;
    sm += __expf(e - mx);
  }
  sm += __shfl_xor(sm, 1); sm += __shfl_xor(sm, 2); sm += __shfl_xor(sm, 4);
  const float inv = 1.f/(sm + 1e-16f);

  const int c4 = lane*4;                          // channels [c4, c4+4) ; head c4/32 == h
  f32x4 acc = {0.f,0.f,0.f,0.f};
  for (int j = 0; j < deg; ++j){
    int s = eidx[e0 + j];
    float e = asrc[s*NHD + h] + adv; e = e > 0.f ? e : 0.2f*e;
    float w = __expf(e - mx)*inv;
    short4v gv = *(const short4v*)(gm + (size_t)s*DHC + c4);
    acc.x += w*bf2f((ushort_t)gv.x);
    acc.y += w*bf2f((ushort_t)gv.y);
    acc.z += w*bf2f((ushort_t)gv.z);
    acc.w += w*bf2f((ushort_t)gv.w);
  }
  f32x4 bgv = *(const f32x4*)(bg + c4);
  f32x4 rv  = *(const f32x4*)(res + (size_t)node*DHC + c4);
  f32x4 o;
  #pragma unroll
  for (int q = 0; q < 4; ++q){
    float v = acc[q] + bgv[q];
    v = v > 0.f ? v : expm1f(v);
    o[q] = v + rv[q];
  }
  *(f32x4*)(out + (size_t)node*DHC + c4) = o;
}

extern "C" void kernel_launch(void* const* d_in, const int* in_sizes, int n_in,
                              void* d_out, int out_size, void* d_ws, size_t ws_size,
                              hipStream_t stream){
  (void)in_sizes; (void)n_in; (void)out_size; (void)ws_size;
  const float* x     = (const float*)d_in[0];
  const int*   ei    = (const int*)d_in[1];          // int32 per harness convention
  const float* ln_g  = (const float*)d_in[2];
  const float* ln_b  = (const float*)d_in[3];
  const float* W1    = (const float*)d_in[4];
  const float* b1    = (const float*)d_in[5];
  const float* W2    = (const float*)d_in[6];
  const float* b2    = (const float*)d_in[7];
  const float* Wr    = (const float*)d_in[8];
  const float* br    = (const float*)d_in[9];
  const float* Wg    = (const float*)d_in[10];
  const float* att_s = (const float*)d_in[11];
  const float* att_d = (const float*)d_in[12];
  const float* bg    = (const float*)d_in[13];
  float* out = (float*)d_out;

  char* p = (char*)d_ws;
  // persistent region (ws): xn 153.6MB + h1 102.4MB = 256.0MB
  ushort_t* xn   = (ushort_t*)(p);                   // [0, 153,600,000)
  ushort_t* h1   = (ushort_t*)(p + 153600000);       // 102,400,000 -> 256,000,000
  // transposed weights live in d_out (dead until gat_agg overwrites all of it)
  ushort_t* W1T  = (ushort_t*)d_out;                           // 3,145,728
  ushort_t* W2T  = (ushort_t*)((char*)d_out + 3145728);        // 1,048,576
  ushort_t* WrgT = (ushort_t*)((char*)d_out + 4194304);        //   524,288 -> 4,718,592
  // aliased into xn region (xn dead after gemm1)
  ushort_t* hb   = (ushort_t*)(p + 0);               //  51,200,000 (bf16)
  float*    res  = (float*)(p + 51200000);           //  51,200,000 (f32)
  ushort_t* gm   = (ushort_t*)(p + 102400000);       //  25,600,000 (bf16)
  float*    asrc = (float*)(p + 128000000);          //   1,600,000
  float*    adst = (float*)(p + 129600000);          //   1,600,000
  int*      cnt  = (int*)(p + 131200000);            //     200,000
  int*      offs = (int*)(p + 131400064);            //     200,004
  int*      cur  = (int*)(p + 131600128);            //     200,000
  int*      eidx = (int*)(p + 131800192);            //   3,400,000 -> end 135,200,192

  // weight prep (bf16, transposed, K-padded)
  transpose_cast<<<dim3(48,32), 256, 0, stream>>>(W1, W1T, DIN,  DHID, DINP);
  transpose_cast<<<dim3(32,16), 256, 0, stream>>>(W2, W2T, DHID, DOUT, DHID);
  transpose_cast<<<dim3(16, 8), 256, 0, stream>>>(Wr, WrgT,            DOUT, DHC, DOUT);
  transpose_cast<<<dim3(16, 8), 256, 0, stream>>>(Wg, WrgT + 256*DOUT, DOUT, DHC, DOUT);

  ln_kernel<<<NND, 256, 0, stream>>>(x, ln_g, ln_b, xn);

  const int RB = (NND + 255) / 256;   // 196 row blocks
  gemm_bt<1,1,4><<<RB*4, 512, 0, stream>>>(xn, W1T, b1, h1, nullptr, NND, DHID, DINP);
  gemm_bt<0,1,2><<<RB*2, 512, 0, stream>>>(h1, W2T, b2, hb, nullptr, NND, DOUT, DHID);
  gemm_bt<0,2,2><<<RB*2, 512, 0, stream>>>(hb, WrgT, br, res, gm, NND, 2*DHC, DOUT);

  att_scores<<<(NND*NHD + 255)/256, 256, 0, stream>>>(gm, att_s, att_d, asrc, adst);

  init_cnt<<<(NND + 255)/256, 256, 0, stream>>>(cnt);
  count_edges<<<(NE + 255)/256, 256, 0, stream>>>(ei, cnt);
  scan_kernel<<<1, 1024, 0, stream>>>(cnt, offs, cur);
  fill_self<<<(NND + 255)/256, 256, 0, stream>>>(cur, eidx);
  fill_edges<<<(NE + 255)/256, 256, 0, stream>>>(ei, cur, eidx);

  gat_agg<<<(NND + 3)/4, 256, 0, stream>>>(offs, eidx, asrc, adst, gm, res, bg, out);
}